// Round 17
// baseline (3287.251 us; speedup 1.0000x reference)
//
#include <hip/hip_runtime.h>
#include <cstddef>
#include <cstdint>

// Problem constants (from reference)
#define SEQB   8
#define SEQL   2048
#define DMODEL 1024
#define DINNER 2048
#define DSTATE 16
#define NC     32            // scan chunks along t
#define TC     64            // SEQL/NC
#define TT     8             // scan LDS tile rows (t per stage)

typedef __attribute__((ext_vector_type(4))) float f32x4;
typedef __attribute__((ext_vector_type(8))) short bf16x8;
typedef unsigned int u32;
typedef const __attribute__((address_space(1))) u32* gas_ptr;
typedef __attribute__((address_space(3))) u32* las_ptr;

__device__ __forceinline__ void gld16(const void* g, void* l){
  __builtin_amdgcn_global_load_lds((gas_ptr)g, (las_ptr)l, 16, 0, 0);
}

__device__ __forceinline__ float siluf(float x){ return x / (1.f + __expf(-x)); }
__device__ __forceinline__ float softplusf(float x){ return (x > 20.f) ? x : log1pf(__expf(x)); }

// RNE fp32 -> bf16 bits
__device__ __forceinline__ unsigned short f2bf_rne(float f){
  unsigned int u = __float_as_uint(f);
  u += 0x7FFFu + ((u>>16)&1u);
  return (unsigned short)(u>>16);
}
__device__ __forceinline__ void split_bf(float f, unsigned short& h, unsigned short& l){
  unsigned short hs = f2bf_rne(f);
  float hf = __uint_as_float(((unsigned int)hs)<<16);
  h = hs;
  l = f2bf_rne(f - hf);
}

// Convert 8 consecutive fp32 at PSRC into hi/lo bf16x8; store to PH / PH+64.
#define CV8P(PH, PSRC) { \
  const float4* _p4 = (const float4*)(PSRC); \
  float4 _a = _p4[0], _b = _p4[1]; \
  bf16x8 _H, _L; unsigned short _h,_l; \
  split_bf(_a.x,_h,_l); _H[0]=(short)_h; _L[0]=(short)_l; \
  split_bf(_a.y,_h,_l); _H[1]=(short)_h; _L[1]=(short)_l; \
  split_bf(_a.z,_h,_l); _H[2]=(short)_h; _L[2]=(short)_l; \
  split_bf(_a.w,_h,_l); _H[3]=(short)_h; _L[3]=(short)_l; \
  split_bf(_b.x,_h,_l); _H[4]=(short)_h; _L[4]=(short)_l; \
  split_bf(_b.y,_h,_l); _H[5]=(short)_h; _L[5]=(short)_l; \
  split_bf(_b.z,_h,_l); _H[6]=(short)_h; _L[6]=(short)_l; \
  split_bf(_b.w,_h,_l); _H[7]=(short)_h; _L[7]=(short)_l; \
  *(bf16x8*)(PH) = _H; *(bf16x8*)((unsigned short*)(PH) + 64) = _L; }

// ---------------------------------------------------------------------------
// Weight pre-split PAIR {h|l}: src [R][K] fp32 -> dst [R][2K] bf16.
// ---------------------------------------------------------------------------
__global__ __launch_bounds__(256)
void wsplit2(const float* __restrict__ src, unsigned short* __restrict__ dst,
             int K, int k4shift)
{
  int idx = blockIdx.x*256 + threadIdx.x;
  int r  = idx >> k4shift;
  int c4 = idx & ((1<<k4shift)-1);
  float4 v = ((const float4*)src)[idx];
  unsigned short h,l; short4 h4, l4;
  split_bf(v.x,h,l); h4.x=(short)h; l4.x=(short)l;
  split_bf(v.y,h,l); h4.y=(short)h; l4.y=(short)l;
  split_bf(v.z,h,l); h4.z=(short)h; l4.z=(short)l;
  split_bf(v.w,h,l); h4.w=(short)h; l4.w=(short)l;
  size_t ro = (size_t)r*2*K;
  *(short4*)&dst[ro + (c4<<2)]     = h4;
  *(short4*)&dst[ro + K + (c4<<2)] = l4;
}

// ---------------------------------------------------------------------------
// out_proj weight split, GROUPED pair layout matching scan's gy write.
// ---------------------------------------------------------------------------
__global__ __launch_bounds__(256)
void wsplit_og(const float* __restrict__ src, unsigned short* __restrict__ dst)
{
  int idx = blockIdx.x*256 + threadIdx.x;
  int r  = idx >> 9;
  int c4 = idx & 511;
  int layer = r >> 10, rr = r & 1023;
  float4 v = ((const float4*)src)[idx];
  unsigned short h,l; short4 h4, l4;
  split_bf(v.x,h,l); h4.x=(short)h; l4.x=(short)l;
  split_bf(v.y,h,l); h4.y=(short)h; l4.y=(short)l;
  split_bf(v.z,h,l); h4.z=(short)h; l4.z=(short)l;
  split_bf(v.w,h,l); h4.w=(short)h; l4.w=(short)l;
  int col = c4 << 2;
  int g = col >> 8, j = col & 255;
  size_t base = (size_t)layer*1024*4096 + (size_t)rr*4096 + g*512 + j;
  *(short4*)&dst[base]       = h4;
  *(short4*)&dst[base + 256] = l4;
}

// ---------------------------------------------------------------------------
// LayerNorm (+ optional residual) fused with PAIR split {h|l}.
// ---------------------------------------------------------------------------
__global__ __launch_bounds__(256)
void ln_split2(const float* __restrict__ a, const float* __restrict__ res,
               const float* __restrict__ w, const float* __restrict__ bias,
               unsigned short* __restrict__ Hs)
{
  int row = blockIdx.x;
  size_t off = (size_t)row * DMODEL;
  float4 v = ((const float4*)(a + off))[threadIdx.x];
  if (res){
    float4 u = ((const float4*)(res + off))[threadIdx.x];
    v.x += u.x; v.y += u.y; v.z += u.z; v.w += u.w;
  }
  float s  = v.x + v.y + v.z + v.w;
  float s2 = fmaf(v.x,v.x, fmaf(v.y,v.y, fmaf(v.z,v.z, v.w*v.w)));
  #pragma unroll
  for (int o=32;o>0;o>>=1){ s += __shfl_down(s,o,64); s2 += __shfl_down(s2,o,64); }
  __shared__ float red[8];
  int lane = threadIdx.x & 63, wid = threadIdx.x >> 6;
  if (lane==0){ red[wid]=s; red[4+wid]=s2; }
  __syncthreads();
  s  = red[0]+red[1]+red[2]+red[3];
  s2 = red[4]+red[5]+red[6]+red[7];
  float mu  = s * (1.f/DMODEL);
  float var = s2 * (1.f/DMODEL) - mu*mu;
  float rstd = rsqrtf(var + 1e-5f);
  float4 wv = ((const float4*)w)[threadIdx.x];
  float4 bv = ((const float4*)bias)[threadIdx.x];
  float4 o4;
  o4.x = (v.x-mu)*rstd*wv.x + bv.x;
  o4.y = (v.y-mu)*rstd*wv.y + bv.y;
  o4.z = (v.z-mu)*rstd*wv.z + bv.z;
  o4.w = (v.w-mu)*rstd*wv.w + bv.w;
  unsigned short h,l; short4 h4, l4;
  split_bf(o4.x,h,l); h4.x=(short)h; l4.x=(short)l;
  split_bf(o4.y,h,l); h4.y=(short)h; l4.y=(short)l;
  split_bf(o4.z,h,l); h4.z=(short)h; l4.z=(short)l;
  split_bf(o4.w,h,l); h4.w=(short)h; l4.w=(short)l;
  size_t ro = (size_t)row*2048;
  int c = threadIdx.x<<2;
  *(short4*)&Hs[ro + c]        = h4;
  *(short4*)&Hs[ro + 1024 + c] = l4;
}

// ---------------------------------------------------------------------------
// in_proj GEMM, 256x256 tile, 8 waves, DOUBLE-BUFFERED (128KB LDS) with
// counted vmcnt(8): STAGE(nxt) -> vmcnt(8) -> bar -> 96 MFMA/wave -> bar.
// Epilogue splits cols: bx<8 -> XI, else -> ZB. M mult of 256.
// ---------------------------------------------------------------------------
__global__ __launch_bounds__(512)
void mgemm_in8(const unsigned short* __restrict__ A,   // [M][2048] {h|l}
               const unsigned short* __restrict__ B,   // [4096][2048] {h|l}
               float* __restrict__ XI, float* __restrict__ ZB)
{
  __shared__ __align__(16) unsigned short As[2][256*64];
  __shared__ __align__(16) unsigned short Bs[2][256*64];
  const int t = threadIdx.x;
  const int mbase = blockIdx.y << 8, nbase = blockIdx.x << 8;
  const int lane = t & 63, w = t >> 6;          // 8 waves
  const int wr = w & 3, wc = w >> 2;            // 4x2 wave grid
  const int l16 = lane & 15, kq = lane >> 4;

  const int sr8 = lane >> 3, sl8 = lane & 7;
  const unsigned short* pA[4]; const unsigned short* pB[4];
  int dofs[4];
  #pragma unroll
  for (int c=0;c<4;c++){
    int row = w*32 + c*8 + sr8;                 // 0..255
    int ss  = sl8 ^ (row & 7);
    int colb = (ss < 4) ? (ss<<3) : (1024 + ((ss-4)<<3));
    pA[c] = A + (size_t)(mbase+row)*2048 + colb;
    pB[c] = B + (size_t)(nbase+row)*2048 + colb;
    dofs[c] = row*64 + sl8*8;
  }

  f32x4 acc[4][8];
  #pragma unroll
  for (int i=0;i<4;i++)
    #pragma unroll
    for (int j=0;j<8;j++) acc[i][j] = (f32x4){0.f,0.f,0.f,0.f};

#define STG(buf, k0) { _Pragma("unroll") \
    for (int c=0;c<4;c++){ \
      gld16(pA[c] + (k0), &As[buf][dofs[c]]); \
      gld16(pB[c] + (k0), &Bs[buf][dofs[c]]); \
    } }

  STG(0, 0);
  asm volatile("s_waitcnt vmcnt(0)" ::: "memory");
  __builtin_amdgcn_s_barrier();
  __builtin_amdgcn_sched_barrier(0);

  for (int i=0; i<32; i++){
    const int cur = i & 1, nxt = cur ^ 1;
    const bool hn = (i+1 < 32);
    if (hn){
      STG(nxt, (i+1)*32);
      asm volatile("s_waitcnt vmcnt(8)" ::: "memory");
    } else {
      asm volatile("s_waitcnt vmcnt(0)" ::: "memory");
    }
    __builtin_amdgcn_s_barrier();
    __builtin_amdgcn_sched_barrier(0);

    const unsigned short* Ac = As[cur];
    const unsigned short* Bc = Bs[cur];
    bf16x8 ah[4], al[4];
    #pragma unroll
    for (int mf=0; mf<4; mf++){
      int ra = wr*64 + mf*16 + l16;
      ah[mf] = *(const bf16x8*)&Ac[ra*64 + (( kq      ^ (ra&7))<<3)];
      al[mf] = *(const bf16x8*)&Ac[ra*64 + (((kq+4)   ^ (ra&7))<<3)];
    }
    #pragma unroll
    for (int nf=0; nf<8; nf++){
      int rb = wc*128 + nf*16 + l16;
      bf16x8 bh = *(const bf16x8*)&Bc[rb*64 + (( kq    ^ (rb&7))<<3)];
      bf16x8 bl = *(const bf16x8*)&Bc[rb*64 + (((kq+4) ^ (rb&7))<<3)];
      #pragma unroll
      for (int mf=0; mf<4; mf++){
        acc[mf][nf] = __builtin_amdgcn_mfma_f32_16x16x32_bf16(ah[mf], bh, acc[mf][nf], 0,0,0);
        acc[mf][nf] = __builtin_amdgcn_mfma_f32_16x16x32_bf16(ah[mf], bl, acc[mf][nf], 0,0,0);
        acc[mf][nf] = __builtin_amdgcn_mfma_f32_16x16x32_bf16(al[mf], bh, acc[mf][nf], 0,0,0);
      }
    }
    __builtin_amdgcn_s_barrier();
  }
#undef STG

  float* Cd = (nbase < 2048) ? XI : ZB;
  const int cb = (nbase < 2048) ? nbase : (nbase - 2048);
  #pragma unroll
  for (int mf=0; mf<4; mf++){
    int r0 = mbase + wr*64 + mf*16 + kq*4;
    #pragma unroll
    for (int nf=0; nf<8; nf++){
      int c = cb + wc*128 + nf*16 + l16;
      #pragma unroll
      for (int r=0;r<4;r++)
        Cd[(size_t)(r0+r)*2048 + c] = acc[mf][nf][r];
    }
  }
}

// ---------------------------------------------------------------------------
// out_proj GEMM, 256x256 tile, 8 waves, DOUBLE-BUFFERED (128KB) with counted
// vmcnt(8), GROUPED-plane 3-combo windows (64 windows of K=32).
// ---------------------------------------------------------------------------
__global__ __launch_bounds__(512)
void mgemm_out8(const unsigned short* __restrict__ A,   // [M][4096] grouped
                const unsigned short* __restrict__ B,   // [1024][4096] grouped
                float* __restrict__ C)                  // [M][1024]
{
  __shared__ __align__(16) unsigned short As[2][256*64];
  __shared__ __align__(16) unsigned short Bs[2][256*64];
  const int t = threadIdx.x;
  const int mbase = blockIdx.y << 8, nbase = blockIdx.x << 8;
  const int lane = t & 63, w = t >> 6;
  const int wr = w & 3, wc = w >> 2;
  const int l16 = lane & 15, kq = lane >> 4;

  const int sr8 = lane >> 3, sl8 = lane & 7;
  const unsigned short* pA[4]; const unsigned short* pB[4];
  int dofs[4];
  #pragma unroll
  for (int c=0;c<4;c++){
    int row = w*32 + c*8 + sr8;
    int ss  = sl8 ^ (row & 7);
    int pofs = (ss < 4) ? (ss<<3) : (256 + ((ss-4)<<3));
    pA[c] = A + (size_t)(mbase+row)*4096 + pofs;
    pB[c] = B + (size_t)(nbase+row)*4096 + pofs;
    dofs[c] = row*64 + sl8*8;
  }

  f32x4 acc[4][8];
  #pragma unroll
  for (int i=0;i<4;i++)
    #pragma unroll
    for (int j=0;j<8;j++) acc[i][j] = (f32x4){0.f,0.f,0.f,0.f};

#define GSO(i) ((((i)*32)>>8)<<9) + (((i)*32) & 255)
#define STG(buf, i) { const int gso = GSO(i); _Pragma("unroll") \
    for (int c=0;c<4;c++){ \
      gld16(pA[c] + gso, &As[buf][dofs[c]]); \
      gld16(pB[c] + gso, &Bs[buf][dofs[c]]); \
    } }

  STG(0, 0);
  asm volatile("s_waitcnt vmcnt(0)" ::: "memory");
  __builtin_amdgcn_s_barrier();
  __builtin_amdgcn_sched_barrier(0);

  for (int i=0; i<64; i++){
    const int cur = i & 1, nxt = cur ^ 1;
    const bool hn = (i+1 < 64);
    if (hn){
      STG(nxt, i+1);
      asm volatile("s_waitcnt vmcnt(8)" ::: "memory");
    } else {
      asm volatile("s_waitcnt vmcnt(0)" ::: "memory");
    }
    __builtin_amdgcn_s_barrier();
    __builtin_amdgcn_sched_barrier(0);

    const unsigned short* Ac = As[cur];
    const unsigned short* Bc = Bs[cur];
    bf16x8 ah[4], al[4];
    #pragma unroll
    for (int mf=0; mf<4; mf++){
      int ra = wr*64 + mf*16 + l16;
      ah[mf] = *(const bf16x8*)&Ac[ra*64 + (( kq      ^ (ra&7))<<3)];
      al[mf] = *(const bf16x8*)&Ac[ra*64 + (((kq+4)   ^ (ra&7))<<3)];
    }
    #pragma unroll
    for (int nf=0; nf<8; nf++){
      int rb = wc*128 + nf*16 + l16;
      bf16x8 bh = *(const bf16x8*)&Bc[rb*64 + (( kq    ^ (rb&7))<<3)];
      bf16x8 bl = *(const bf16x8*)&Bc[rb*64 + (((kq+4) ^ (rb&7))<<3)];
      #pragma unroll
      for (int mf=0; mf<4; mf++){
        acc[mf][nf] = __builtin_amdgcn_mfma_f32_16x16x32_bf16(ah[mf], bh, acc[mf][nf], 0,0,0);
        acc[mf][nf] = __builtin_amdgcn_mfma_f32_16x16x32_bf16(ah[mf], bl, acc[mf][nf], 0,0,0);
        acc[mf][nf] = __builtin_amdgcn_mfma_f32_16x16x32_bf16(al[mf], bh, acc[mf][nf], 0,0,0);
      }
    }
    __builtin_amdgcn_s_barrier();
  }
#undef STG
#undef GSO

  #pragma unroll
  for (int mf=0; mf<4; mf++){
    int r0 = mbase + wr*64 + mf*16 + kq*4;
    #pragma unroll
    for (int nf=0; nf<8; nf++){
      int c = nbase + wc*128 + nf*16 + l16;
      #pragma unroll
      for (int r=0;r<4;r++)
        C[(size_t)(r0+r)*1024 + c] = acc[mf][nf][r];
    }
  }
}

// ---------------------------------------------------------------------------
// x_proj GEMM, single-staged 3-combo + double-buffered counted-vmcnt (r15).
// ---------------------------------------------------------------------------
__global__ __launch_bounds__(256)
void xproj_pair(const unsigned short* __restrict__ A,   // U2 [M][4096] {h|l}
                const unsigned short* __restrict__ W2,  // [96][4096] {h|l}
                float* __restrict__ XD)
{
  __shared__ __align__(16) unsigned short S[2][128*64];
  const int t = threadIdx.x;
  const int mbase = blockIdx.x << 5;
  const int lane = t & 63, w = t >> 6;
  const int mf = w & 1, nc0 = (w >> 1) * 48;
  const int l16 = lane & 15, kq = lane >> 4;

  const unsigned short* ps[4]; int dofs[4];
  #pragma unroll
  for (int c=0;c<4;c++){
    int idx = c*256 + t;
    int row = idx >> 3, sl8 = idx & 7;
    int ss  = sl8 ^ (row & 7);
    int colb = (ss < 4) ? (ss<<3) : (2048 + ((ss-4)<<3));
    ps[c] = (row < 32) ? (A + (size_t)(mbase+row)*4096 + colb)
                       : (W2 + (size_t)(row-32)*4096 + colb);
    dofs[c] = row*64 + sl8*8;
  }

  f32x4 acc[3];
  #pragma unroll
  for (int j=0;j<3;j++) acc[j] = (f32x4){0.f,0.f,0.f,0.f};

#define STG(buf, k0) { _Pragma("unroll") \
    for (int c=0;c<4;c++) gld16(ps[c] + (k0), &S[buf][dofs[c]]); }

  STG(0, 0);
  asm volatile("s_waitcnt vmcnt(0)" ::: "memory");
  __builtin_amdgcn_s_barrier();
  __builtin_amdgcn_sched_barrier(0);

  for (int i=0; i<64; i++){
    const int cur = i & 1, nxt = cur ^ 1;
    const bool hn = (i+1 < 64);
    if (hn){
      STG(nxt, (i+1)*32);
      asm volatile("s_waitcnt vmcnt(4)" ::: "memory");
    } else {
      asm volatile("s_waitcnt vmcnt(0)" ::: "memory");
    }
    __builtin_amdgcn_s_barrier();
    __builtin_amdgcn_sched_barrier(0);

    const unsigned short* Sc = S[cur];
    int ra = mf*16 + l16;
    bf16x8 ah = *(const bf16x8*)&Sc[ra*64 + (( kq    ^ (ra&7))<<3)];
    bf16x8 al = *(const bf16x8*)&Sc[ra*64 + (((kq+4) ^ (ra&7))<<3)];
    #pragma unroll
    for (int nf=0; nf<3; nf++){
      int rb = 32 + nc0 + nf*16 + l16;
      bf16x8 bh = *(const bf16x8*)&Sc[rb*64 + (( kq    ^ (rb&7))<<3)];
      bf16x8 bl = *(const bf16x8*)&Sc[rb*64 + (((kq+4) ^ (rb&7))<<3)];
      acc[nf] = __builtin_amdgcn_mfma_f32_16x16x32_bf16(ah, bh, acc[nf], 0,0,0);
      acc[nf] = __builtin_amdgcn_mfma_f32_16x16x32_bf16(ah, bl, acc[nf], 0,0,0);
      acc[nf] = __builtin_amdgcn_mfma_f32_16x16x32_bf16(al, bh, acc[nf], 0,0,0);
    }
    __builtin_amdgcn_s_barrier();
  }
#undef STG

  #pragma unroll
  for (int nf=0; nf<3; nf++){
    int c = nc0 + nf*16 + l16;
    int r0s = mbase + mf*16 + kq*4;
    #pragma unroll
    for (int r=0;r<4;r++)
      XD[(size_t)(r0s+r)*96 + c] = acc[nf][r];
  }
}

// ---------------------------------------------------------------------------
// dt_proj MFMA (r14 proven): K=64 fully staged once, 96 MFMAs, softplus.
// ---------------------------------------------------------------------------
__global__ __launch_bounds__(256)
void mgemm_dt2(const float* __restrict__ XDf,           // [M][96], cols 0..63
               const unsigned short* __restrict__ DTW2, // [2048][128] pair
               float* __restrict__ XI,
               const float* __restrict__ dtb)
{
  __shared__ __align__(16) unsigned short As[128*128];
  __shared__ __align__(16) unsigned short Bs[128*128];
  const int t = threadIdx.x;
  const int mbase = blockIdx.y << 7, nbase = blockIdx.x << 7;
  const int lane = t & 63, w = t >> 6;
  const int wr = w >> 1, wc = w & 1;
  const int l16 = lane & 15, kq = lane >> 4;

  {
    const int row = t >> 1, half = (t & 1) << 5;
    const int r7 = row & 7;
    const float* src = XDf + (size_t)(mbase + row)*96 + half;
    #pragma unroll
    for (int i=0;i<4;i++){
      int g = (half >> 3) + i;
      CV8P(&As[row*128 + ((g ^ r7)<<3)], src + i*8);
    }
  }
  {
    #pragma unroll
    for (int q=0;q<8;q++){
      int idx = q*256 + t;
      int row = idx >> 4, sl = idx & 15;
      int ss  = (sl & 8) | ((sl & 7) ^ (row & 7));
      int col = (ss < 8) ? (ss<<3) : (64 + ((ss-8)<<3));
      gld16(DTW2 + (size_t)(nbase+row)*128 + col, &Bs[row*128 + sl*8]);
    }
  }
  __syncthreads();

  f32x4 acc[4][4];
  #pragma unroll
  for (int i=0;i<4;i++)
    #pragma unroll
    for (int j=0;j<4;j++) acc[i][j] = (f32x4){0.f,0.f,0.f,0.f};

  #pragma unroll
  for (int kb=0; kb<3; kb++){
    const int aoff = (kb==2) ? 8 : 0;
    const int boff = (kb==1) ? 8 : 0;
    #pragma unroll
    for (int kw=0; kw<2; kw++){
      const int sbase = kw*4 + kq;
      bf16x8 af[4];
      #pragma unroll
      for (int mf=0; mf<4; mf++){
        int ra = wr*64 + mf*16 + l16;
        int sA = ((sbase ^ (ra&7)) + aoff);
        af[mf] = *(const bf16x8*)&As[ra*128 + (sA<<3)];
      }
      #pragma unroll
      for (int nf=0; nf<4; nf++){
        int rb = wc*64 + nf*16 + l16;
        int sB = ((sbase ^ (rb&7)) + boff);
        bf16x8 bfr = *(const bf16x8*)&Bs[rb*128 + (sB<<3)];
        #pragma unroll
        for (int mf=0; mf<4; mf++)
          acc[mf][nf] = __builtin_amdgcn_mfma_f32_16x16x32_bf16(af[mf], bfr, acc[mf][nf], 0,0,0);
      }
    }
  }

  #pragma unroll
  for (int mf=0; mf<4; mf++){
    int r0 = mbase + wr*64 + mf*16 + kq*4;
    #pragma unroll
    for (int nf=0; nf<4; nf++){
      int c = nbase + wc*64 + nf*16 + l16;
      float eb = dtb[c];
      #pragma unroll
      for (int r=0;r<4;r++)
        XI[(size_t)(r0+r)*2048 + c] = softplusf(acc[mf][nf][r] + eb);
    }
  }
}

// ---------------------------------------------------------------------------
// Causal depthwise conv (k=4) + bias + SiLU: 4 rows x 8 d per thread (r14).
// ---------------------------------------------------------------------------
__global__ __launch_bounds__(256)
void conv_silu4(const float* __restrict__ xi, const float* __restrict__ cw,
                const float* __restrict__ cb, unsigned short* __restrict__ u2)
{
  const int r0 = blockIdx.x << 2;
  const int d0 = threadIdx.x << 3;
  const int tt0 = r0 & (SEQL-1);

  float wk[4][8];
  {
    const float4* cw4 = (const float4*)(cw + (size_t)d0*4);
    #pragma unroll
    for (int j=0;j<8;j++){
      float4 wj = cw4[j];
      wk[0][j]=wj.x; wk[1][j]=wj.y; wk[2][j]=wj.z; wk[3][j]=wj.w;
    }
  }
  float bias[8];
  *(float4*)&bias[0] = *(const float4*)(cb + d0);
  *(float4*)&bias[4] = *(const float4*)(cb + d0 + 4);

  float v[7][8];
#define LD8(dst, p) { *(float4*)&dst[0] = ((const float4*)(p))[0]; \
                      *(float4*)&dst[4] = ((const float4*)(p))[1]; }
  #pragma unroll
  for (int k=0;k<7;k++){
    int trel = tt0 - 3 + k;
    if (trel >= 0){
      LD8(v[k], xi + (size_t)(r0 - 3 + k)*DINNER + d0);
    } else {
      #pragma unroll
      for (int j=0;j<8;j++) v[k][j] = 0.f;
    }
  }
#undef LD8

  #pragma unroll
  for (int jrow=0; jrow<4; jrow++){
    unsigned short h8[8], l8[8];
    #pragma unroll
    for (int j=0;j<8;j++){
      float y = fmaf(v[jrow+3][j], wk[3][j], fmaf(v[jrow+2][j], wk[2][j],
                fmaf(v[jrow+1][j], wk[1][j], fmaf(v[jrow][j], wk[0][j], bias[j]))));
      float uv = siluf(y);
      split_bf(uv, h8[j], l8[j]);
    }
    unsigned short* outp = u2 + (size_t)(r0 + jrow)*4096 + d0;
    *(uint4*)outp          = *(const uint4*)h8;
    *(uint4*)(outp + 2048) = *(const uint4*)l8;
  }
}

// ---------------------------------------------------------------------------
// Chunked selective scan, PIPELINED double-buffer (r12 proven, unchanged).
// ---------------------------------------------------------------------------
template<int PASS>
__global__ __launch_bounds__(256)
void scan_chunk(const unsigned short* __restrict__ u2, float* __restrict__ dty,
                const float* __restrict__ xdbl, const float* __restrict__ zb,
                const float* __restrict__ A_log, const float* __restrict__ Dp,
                float* __restrict__ hfin, float* __restrict__ sumdt)
{
  __shared__ __align__(16) float Tdt[2][TT][256];
  __shared__ __align__(16) float Tu [2][TT][256];
  __shared__ __align__(16) float Tz [(PASS==3)?2:1][(PASS==3)?TT:1][(PASS==3)?256:4];
  __shared__ __align__(16) float Tbc[2][TT][32];

  const int tid = threadIdx.x;
  const int idx = blockIdx.x*256 + tid;
  const int d = idx & (DINNER-1);
  const int g = idx >> 11;          // uniform per block
  const int cck = g & (NC-1);
  const int bb = g >> 5;
  const int wv = tid >> 6, ln = tid & 63;
  const int dbase = (blockIdx.x << 8) & (DINNER-1);

  float A2[16];
  {
    const float* al = A_log + (size_t)d*DSTATE;
    #pragma unroll
    for (int s=0;s<16;s++) A2[s] = -expf(al[s]) * 1.44269504f;
  }
  float h[16];
  if (PASS == 1){
    #pragma unroll
    for (int s=0;s<16;s++) h[s] = 0.f;
  } else {
    const float* hp = hfin + ((size_t)g*DINNER + d)*16;
    #pragma unroll
    for (int s=0;s<16;s+=4) *(float4*)&h[s] = *(const float4*)(hp + s);
  }
  const float Dv = (PASS==3) ? Dp[d] : 0.f;

  const size_t row0 = (size_t)bb*SEQL + (size_t)cck*TC;

#define STAGE(buf, T0) do { \
    _Pragma("unroll") \
    for (int q=0;q<2;q++){ \
      int r = q*4 + wv; \
      size_t rowi = row0 + (T0) + r; \
      gld16(dty + rowi*2048 + dbase + ln*4, &Tdt[buf][r][0]); \
      const unsigned short* us = u2 + rowi*4096 + \
          ((ln < 32) ? (dbase + ln*8) : (2048 + dbase + (ln-32)*8)); \
      gld16(us, &Tu[buf][r][0]); \
      if (PASS==3) gld16(zb + rowi*2048 + dbase + ln*4, &Tz[buf][r][0]); \
    } \
    if (wv == 3){ \
      gld16(xdbl + (row0 + (T0) + (ln>>3))*96 + 64 + (ln&7)*4, &Tbc[buf][0][0]); \
    } \
  } while(0)

  STAGE(0, 0);
  asm volatile("s_waitcnt vmcnt(0)" ::: "memory");
  __builtin_amdgcn_s_barrier();
  __builtin_amdgcn_sched_barrier(0);

  float sdt = 0.f;

  for (int t0 = 0; t0 < TC; t0 += TT){
    const int cur = (t0 >> 3) & 1, nxt = cur ^ 1;
    const bool hasNext = (t0 + TT < TC);
    if (hasNext) STAGE(nxt, t0 + TT);

    if (hasNext){
      if (PASS==3){
        if (wv==3) asm volatile("s_waitcnt vmcnt(7)" ::: "memory");
        else       asm volatile("s_waitcnt vmcnt(6)" ::: "memory");
      } else {
        if (wv==3) asm volatile("s_waitcnt vmcnt(5)" ::: "memory");
        else       asm volatile("s_waitcnt vmcnt(4)" ::: "memory");
      }
    } else {
      asm volatile("s_waitcnt vmcnt(0)" ::: "memory");
    }
    __builtin_amdgcn_s_barrier();
    __builtin_amdgcn_sched_barrier(0);

    #pragma unroll
    for (int tt=0; tt<TT; tt++){
      float dtc = Tdt[cur][tt][tid];
      const unsigned short* tur = (const unsigned short*)&Tu[cur][tt][0];
      float uc = __uint_as_float((u32)tur[tid] << 16)
               + __uint_as_float((u32)tur[256+tid] << 16);
      float Bv[16], Cv[16];
      #pragma unroll
      for (int q=0;q<4;q++) *(float4*)&Bv[q*4] = *(const float4*)&Tbc[cur][tt][q*4];
      if (PASS==3){
        #pragma unroll
        for (int q=0;q<4;q++) *(float4*)&Cv[q*4] = *(const float4*)&Tbc[cur][tt][16+q*4];
      }
      if (PASS==1) sdt += dtc;
      float du = dtc*uc;
      float y = 0.f;
      #pragma unroll
      for (int s=0;s<16;s++){
        float dA = exp2f(dtc*A2[s]);
        h[s] = fmaf(dA, h[s], du*Bv[s]);
        if (PASS==3) y = fmaf(h[s], Cv[s], y);
      }
      if (PASS==3){
        float zc = Tz[cur][tt][tid];
        y = fmaf(uc, Dv, y);
        float gv = y * siluf(zc);
        unsigned short gh, gl;
        split_bf(gv, gh, gl);
        Tdt[cur][tt][tid] = __uint_as_float((u32)gh | ((u32)gl << 16));
      }
    }

    if (PASS==3) asm volatile("s_waitcnt lgkmcnt(0)" ::: "memory");
    __builtin_amdgcn_s_barrier();
    __builtin_amdgcn_sched_barrier(0);

    if (PASS==3){
      #pragma unroll
      for (int q=0;q<2;q++){
        int r = q*4 + wv;
        size_t rowi = row0 + t0 + r;
        const u32* T = (const u32*)&Tdt[cur][r][0];
        int o0 = ln*4;
        u32 vals[4];
        if (ln < 32){
          #pragma unroll
          for (int k=0;k<4;k++){
            int i2 = (o0+k)*2;
            vals[k] = (T[i2] & 0xFFFFu) | (T[i2+1] << 16);
          }
        } else {
          #pragma unroll
          for (int k=0;k<4;k++){
            int i2 = (o0+k-128)*2;
            vals[k] = (T[i2] >> 16) | (T[i2+1] & 0xFFFF0000u);
          }
        }
        *(float4*)(dty + rowi*2048 + dbase + o0) = *(const float4*)vals;
      }
    }
  }
#undef STAGE

  if (PASS==1){
    float* hp = hfin + ((size_t)g*DINNER + d)*16;
    #pragma unroll
    for (int s=0;s<16;s+=4) *(float4*)(hp + s) = *(const float4*)&h[s];
    sumdt[(size_t)g*DINNER + d] = sdt;
  }
}

// ---------------------------------------------------------------------------
// Propagate chunk-initial states: in-place hfin[c] := H_init(c).
// ---------------------------------------------------------------------------
__global__ __launch_bounds__(256)
void scan_prop(const float* __restrict__ A_log, float* __restrict__ hfin,
               const float* __restrict__ sumdt)
{
  int idx = blockIdx.x*256 + threadIdx.x;
  int s = idx & 15;
  int d = (idx >> 4) & (DINNER-1);
  int b = idx >> 15;
  float A2 = -expf(A_log[(size_t)d*DSTATE + s]) * 1.44269504f;
  float H = 0.f;
  size_t hbase = ((size_t)b*NC*DINNER + d)*16 + s;
  size_t sbase = (size_t)b*NC*DINNER + d;
  for (int c=0;c<NC;c++){
    float P   = exp2f(A2 * sumdt[sbase + (size_t)c*DINNER]);
    float tmp = hfin[hbase + (size_t)c*DINNER*16];
    hfin[hbase + (size_t)c*DINNER*16] = H;
    H = fmaf(P, H, tmp);
  }
}

// ---------------------------------------------------------------------------
// Launcher.  Fixed (52.95 MB): INW2 33.55 + OUTWG 16.78 + XPW2 1.57 +
// DTW2 1.05.  Per batch (58.72 MB).  NB=4 -> 287.8 MB (< 305.1 known-good).
// ---------------------------------------------------------------------------
extern "C" void kernel_launch(void* const* d_in, const int* in_sizes, int n_in,
                              void* d_out, int out_size, void* d_ws, size_t ws_size,
                              hipStream_t stream)
{
  const float* x    = (const float*)d_in[0];
  const float* in_w = (const float*)d_in[1];
  const float* cw   = (const float*)d_in[2];
  const float* cb   = (const float*)d_in[3];
  const float* xpw  = (const float*)d_in[4];
  const float* dtw  = (const float*)d_in[5];
  const float* dtb  = (const float*)d_in[6];
  const float* A_log= (const float*)d_in[7];
  const float* Dp   = (const float*)d_in[8];
  const float* ow   = (const float*)d_in[9];
  const float* nw   = (const float*)d_in[10];
  const float* nb   = (const float*)d_in[11];
  float* outF = (float*)d_out;

  const size_t fixedB = 33554432ULL + 16777216ULL + 1572864ULL + 1048576ULL;
  const size_t perB   = 58720256ULL;
  int NB = 4;
  while (NB > 1 && fixedB + (size_t)NB*perB > ws_size) NB >>= 1;
  const int Mc = NB * SEQL;
  const int nchunk = SEQB / NB;

  unsigned short* INW2  = (unsigned short*)d_ws;                 // [2][4096][2048]
  unsigned short* OUTWG = INW2 + (size_t)2*4096*2048;            // [2][1024][4096]
  unsigned short* XPW2  = OUTWG + (size_t)2*1024*4096;           // [2][96][4096]
  unsigned short* DTW2  = XPW2 + (size_t)2*96*4096;              // [2][2048][128]
  char* dyn = (char*)(DTW2 + (size_t)2*2048*128);

  unsigned short* SH = (unsigned short*)dyn;                     // Mc*2048 ushort
  float* XD = (float*)dyn;                                       // Mc*96  (alias SH)
  float* HF = (float*)(dyn + (size_t)Mc*384);                    // Mc*512 (alias SH)
  float* SD = (float*)(dyn + (size_t)Mc*2432);                   // Mc*32  (alias SH)
  float* XI = (float*)(dyn + (size_t)Mc*4096);                   // Mc*2048 f32
  float* ZB = XI + (size_t)Mc*2048;                              // Mc*2048
  unsigned short* U2 = (unsigned short*)(ZB + (size_t)Mc*2048);  // Mc*4096 ushort

  // Weight pre-splits
  wsplit2<<<8192, 256, 0, stream>>>(in_w, INW2, 1024, 8);
  wsplit2<<<384,  256, 0, stream>>>(xpw,  XPW2, 2048, 9);
  wsplit2<<<256,  256, 0, stream>>>(dtw,  DTW2, 64, 4);
  wsplit_og<<<4096, 256, 0, stream>>>(ow, OUTWG);

  for (int c = 0; c < nchunk; ++c){
    const size_t rowoff = (size_t)c * Mc;
    const float* xrows = x + rowoff * DMODEL;
    float* X1 = outF + rowoff * DMODEL;     // layer-0 out / final out rows

    for (int l = 0; l < 2; ++l){
      const float* Al = A_log + (size_t)l*DINNER*DSTATE;

      // 1. LayerNorm (+ residual for layer 1) -> SH pair
      ln_split2<<<Mc, 256, 0, stream>>>(
          (l==0) ? xrows : X1, (l==0) ? nullptr : xrows,
          nw + (size_t)l*DMODEL, nb + (size_t)l*DMODEL, SH);

      // 2. in_proj fused xi|z (256x256, dbuf+vmcnt): cols<2048 -> XI else ZB
      mgemm_in8<<<dim3(16, Mc/256), 512, 0, stream>>>(
          SH, INW2 + (size_t)l*4096*2048, XI, ZB);

      // 3. causal conv + bias + SiLU: XI -> U2 (split pair), 4-row threads
      conv_silu4<<<Mc/4, 256, 0, stream>>>(
          XI, cw + (size_t)l*DINNER*4, cb + (size_t)l*DINNER, U2);

      // 4. x_proj (pipelined pair GEMM) -> XD
      xproj_pair<<<Mc/32, 256, 0, stream>>>(
          U2, XPW2 + (size_t)l*96*4096, XD);

      // 5. dt_proj MFMA + bias + softplus -> XI (xi dead after conv)
      mgemm_dt2<<<dim3(16, Mc/128), 256, 0, stream>>>(
          XD, DTW2 + (size_t)l*2048*128, XI, dtb + (size_t)l*DINNER);

      // 6. chunked scan (pipelined); pass 3 writes grouped-plane gy over XI
      scan_chunk<1><<<NB*NC*8, 256, 0, stream>>>(
          U2, XI, XD, ZB, Al, Dp + (size_t)l*DINNER, HF, SD);
      scan_prop<<<NB*128, 256, 0, stream>>>(Al, HF, SD);
      scan_chunk<3><<<NB*NC*8, 256, 0, stream>>>(
          U2, XI, XD, ZB, Al, Dp + (size_t)l*DINNER, HF, SD);

      // 7. out_proj (256x256, dbuf+vmcnt): grouped-A x grouped-B -> X1 rows
      mgemm_out8<<<dim3(4, Mc/256), 512, 0, stream>>>(
          (const unsigned short*)XI, OUTWG + (size_t)l*1024*4096, X1);
    }
  }
}

// Round 18
// 3141.172 us; speedup vs baseline: 1.0465x; 1.0465x over previous
//
#include <hip/hip_runtime.h>
#include <cstddef>
#include <cstdint>

// Problem constants (from reference)
#define SEQB   8
#define SEQL   2048
#define DMODEL 1024
#define DINNER 2048
#define DSTATE 16
#define NC     32            // scan chunks along t
#define TC     64            // SEQL/NC
#define TT     8             // scan LDS tile rows (t per stage)

typedef __attribute__((ext_vector_type(4))) float f32x4;
typedef __attribute__((ext_vector_type(8))) short bf16x8;
typedef unsigned int u32;
typedef const __attribute__((address_space(1))) u32* gas_ptr;
typedef __attribute__((address_space(3))) u32* las_ptr;

__device__ __forceinline__ void gld16(const void* g, void* l){
  __builtin_amdgcn_global_load_lds((gas_ptr)g, (las_ptr)l, 16, 0, 0);
}

__device__ __forceinline__ float siluf(float x){ return x / (1.f + __expf(-x)); }
__device__ __forceinline__ float softplusf(float x){ return (x > 20.f) ? x : log1pf(__expf(x)); }

// RNE fp32 -> bf16 bits
__device__ __forceinline__ unsigned short f2bf_rne(float f){
  unsigned int u = __float_as_uint(f);
  u += 0x7FFFu + ((u>>16)&1u);
  return (unsigned short)(u>>16);
}
__device__ __forceinline__ void split_bf(float f, unsigned short& h, unsigned short& l){
  unsigned short hs = f2bf_rne(f);
  float hf = __uint_as_float(((unsigned int)hs)<<16);
  h = hs;
  l = f2bf_rne(f - hf);
}

// Convert 8 consecutive fp32 at PSRC into hi/lo bf16x8; store to PH / PH+64.
#define CV8P(PH, PSRC) { \
  const float4* _p4 = (const float4*)(PSRC); \
  float4 _a = _p4[0], _b = _p4[1]; \
  bf16x8 _H, _L; unsigned short _h,_l; \
  split_bf(_a.x,_h,_l); _H[0]=(short)_h; _L[0]=(short)_l; \
  split_bf(_a.y,_h,_l); _H[1]=(short)_h; _L[1]=(short)_l; \
  split_bf(_a.z,_h,_l); _H[2]=(short)_h; _L[2]=(short)_l; \
  split_bf(_a.w,_h,_l); _H[3]=(short)_h; _L[3]=(short)_l; \
  split_bf(_b.x,_h,_l); _H[4]=(short)_h; _L[4]=(short)_l; \
  split_bf(_b.y,_h,_l); _H[5]=(short)_h; _L[5]=(short)_l; \
  split_bf(_b.z,_h,_l); _H[6]=(short)_h; _L[6]=(short)_l; \
  split_bf(_b.w,_h,_l); _H[7]=(short)_h; _L[7]=(short)_l; \
  *(bf16x8*)(PH) = _H; *(bf16x8*)((unsigned short*)(PH) + 64) = _L; }

// ---------------------------------------------------------------------------
// Weight pre-split PAIR {h|l}: src [R][K] fp32 -> dst [R][2K] bf16.
// ---------------------------------------------------------------------------
__global__ __launch_bounds__(256)
void wsplit2(const float* __restrict__ src, unsigned short* __restrict__ dst,
             int K, int k4shift)
{
  int idx = blockIdx.x*256 + threadIdx.x;
  int r  = idx >> k4shift;
  int c4 = idx & ((1<<k4shift)-1);
  float4 v = ((const float4*)src)[idx];
  unsigned short h,l; short4 h4, l4;
  split_bf(v.x,h,l); h4.x=(short)h; l4.x=(short)l;
  split_bf(v.y,h,l); h4.y=(short)h; l4.y=(short)l;
  split_bf(v.z,h,l); h4.z=(short)h; l4.z=(short)l;
  split_bf(v.w,h,l); h4.w=(short)h; l4.w=(short)l;
  size_t ro = (size_t)r*2*K;
  *(short4*)&dst[ro + (c4<<2)]     = h4;
  *(short4*)&dst[ro + K + (c4<<2)] = l4;
}

// ---------------------------------------------------------------------------
// out_proj weight split, GROUPED pair layout matching scan's gy write.
// ---------------------------------------------------------------------------
__global__ __launch_bounds__(256)
void wsplit_og(const float* __restrict__ src, unsigned short* __restrict__ dst)
{
  int idx = blockIdx.x*256 + threadIdx.x;
  int r  = idx >> 9;
  int c4 = idx & 511;
  int layer = r >> 10, rr = r & 1023;
  float4 v = ((const float4*)src)[idx];
  unsigned short h,l; short4 h4, l4;
  split_bf(v.x,h,l); h4.x=(short)h; l4.x=(short)l;
  split_bf(v.y,h,l); h4.y=(short)h; l4.y=(short)l;
  split_bf(v.z,h,l); h4.z=(short)h; l4.z=(short)l;
  split_bf(v.w,h,l); h4.w=(short)h; l4.w=(short)l;
  int col = c4 << 2;
  int g = col >> 8, j = col & 255;
  size_t base = (size_t)layer*1024*4096 + (size_t)rr*4096 + g*512 + j;
  *(short4*)&dst[base]       = h4;
  *(short4*)&dst[base + 256] = l4;
}

// ---------------------------------------------------------------------------
// LayerNorm (+ optional residual) fused with PAIR split {h|l}.
// ---------------------------------------------------------------------------
__global__ __launch_bounds__(256)
void ln_split2(const float* __restrict__ a, const float* __restrict__ res,
               const float* __restrict__ w, const float* __restrict__ bias,
               unsigned short* __restrict__ Hs)
{
  int row = blockIdx.x;
  size_t off = (size_t)row * DMODEL;
  float4 v = ((const float4*)(a + off))[threadIdx.x];
  if (res){
    float4 u = ((const float4*)(res + off))[threadIdx.x];
    v.x += u.x; v.y += u.y; v.z += u.z; v.w += u.w;
  }
  float s  = v.x + v.y + v.z + v.w;
  float s2 = fmaf(v.x,v.x, fmaf(v.y,v.y, fmaf(v.z,v.z, v.w*v.w)));
  #pragma unroll
  for (int o=32;o>0;o>>=1){ s += __shfl_down(s,o,64); s2 += __shfl_down(s2,o,64); }
  __shared__ float red[8];
  int lane = threadIdx.x & 63, wid = threadIdx.x >> 6;
  if (lane==0){ red[wid]=s; red[4+wid]=s2; }
  __syncthreads();
  s  = red[0]+red[1]+red[2]+red[3];
  s2 = red[4]+red[5]+red[6]+red[7];
  float mu  = s * (1.f/DMODEL);
  float var = s2 * (1.f/DMODEL) - mu*mu;
  float rstd = rsqrtf(var + 1e-5f);
  float4 wv = ((const float4*)w)[threadIdx.x];
  float4 bv = ((const float4*)bias)[threadIdx.x];
  float4 o4;
  o4.x = (v.x-mu)*rstd*wv.x + bv.x;
  o4.y = (v.y-mu)*rstd*wv.y + bv.y;
  o4.z = (v.z-mu)*rstd*wv.z + bv.z;
  o4.w = (v.w-mu)*rstd*wv.w + bv.w;
  unsigned short h,l; short4 h4, l4;
  split_bf(o4.x,h,l); h4.x=(short)h; l4.x=(short)l;
  split_bf(o4.y,h,l); h4.y=(short)h; l4.y=(short)l;
  split_bf(o4.z,h,l); h4.z=(short)h; l4.z=(short)l;
  split_bf(o4.w,h,l); h4.w=(short)h; l4.w=(short)l;
  size_t ro = (size_t)row*2048;
  int c = threadIdx.x<<2;
  *(short4*)&Hs[ro + c]        = h4;
  *(short4*)&Hs[ro + 1024 + c] = l4;
}

// ---------------------------------------------------------------------------
// in_proj GEMM, 256x256 tile, 8 waves (512 thr), wave tile 64x128.
// Single-staged 3-combo windows; LDS = 64KB (2 blocks/CU -> TLP covers
// stage latency; r16-proven at ~105us). Epilogue: bx<8 -> XI, else -> ZB.
// ---------------------------------------------------------------------------
__global__ __launch_bounds__(512)
void mgemm_in8(const unsigned short* __restrict__ A,   // [M][2048] {h|l}
               const unsigned short* __restrict__ B,   // [4096][2048] {h|l}
               float* __restrict__ XI, float* __restrict__ ZB)
{
  __shared__ __align__(16) unsigned short As[256*64];
  __shared__ __align__(16) unsigned short Bs[256*64];
  const int t = threadIdx.x;
  const int mbase = blockIdx.y << 8, nbase = blockIdx.x << 8;
  const int lane = t & 63, w = t >> 6;          // 8 waves
  const int wr = w & 3, wc = w >> 2;            // 4x2 wave grid
  const int l16 = lane & 15, kq = lane >> 4;

  const int sr8 = lane >> 3, sl8 = lane & 7;
  const unsigned short* pA[4]; const unsigned short* pB[4];
  int dofs[4];
  #pragma unroll
  for (int c=0;c<4;c++){
    int row = w*32 + c*8 + sr8;                 // 0..255
    int ss  = sl8 ^ (row & 7);
    int colb = (ss < 4) ? (ss<<3) : (1024 + ((ss-4)<<3));
    pA[c] = A + (size_t)(mbase+row)*2048 + colb;
    pB[c] = B + (size_t)(nbase+row)*2048 + colb;
    dofs[c] = row*64 + sl8*8;
  }

  f32x4 acc[4][8];
  #pragma unroll
  for (int i=0;i<4;i++)
    #pragma unroll
    for (int j=0;j<8;j++) acc[i][j] = (f32x4){0.f,0.f,0.f,0.f};

  for (int k0=0; k0<1024; k0+=32){
    #pragma unroll
    for (int c=0;c<4;c++){
      gld16(pA[c] + k0, &As[dofs[c]]);
      gld16(pB[c] + k0, &Bs[dofs[c]]);
    }
    __syncthreads();
    bf16x8 ah[4], al[4];
    #pragma unroll
    for (int mf=0; mf<4; mf++){
      int ra = wr*64 + mf*16 + l16;
      ah[mf] = *(const bf16x8*)&As[ra*64 + (( kq      ^ (ra&7))<<3)];
      al[mf] = *(const bf16x8*)&As[ra*64 + (((kq+4)   ^ (ra&7))<<3)];
    }
    #pragma unroll
    for (int nf=0; nf<8; nf++){
      int rb = wc*128 + nf*16 + l16;
      bf16x8 bh = *(const bf16x8*)&Bs[rb*64 + (( kq    ^ (rb&7))<<3)];
      bf16x8 bl = *(const bf16x8*)&Bs[rb*64 + (((kq+4) ^ (rb&7))<<3)];
      #pragma unroll
      for (int mf=0; mf<4; mf++){
        acc[mf][nf] = __builtin_amdgcn_mfma_f32_16x16x32_bf16(ah[mf], bh, acc[mf][nf], 0,0,0);
        acc[mf][nf] = __builtin_amdgcn_mfma_f32_16x16x32_bf16(ah[mf], bl, acc[mf][nf], 0,0,0);
        acc[mf][nf] = __builtin_amdgcn_mfma_f32_16x16x32_bf16(al[mf], bh, acc[mf][nf], 0,0,0);
      }
    }
    __syncthreads();
  }

  float* Cd = (nbase < 2048) ? XI : ZB;
  const int cb = (nbase < 2048) ? nbase : (nbase - 2048);
  #pragma unroll
  for (int mf=0; mf<4; mf++){
    int r0 = mbase + wr*64 + mf*16 + kq*4;
    #pragma unroll
    for (int nf=0; nf<8; nf++){
      int c = cb + wc*128 + nf*16 + l16;
      #pragma unroll
      for (int r=0;r<4;r++)
        Cd[(size_t)(r0+r)*2048 + c] = acc[mf][nf][r];
    }
  }
}

// ---------------------------------------------------------------------------
// out_proj GEMM, 256x128 tile (MxN), 8 waves (512 thr), wave tile 64x64.
// Grid = (8, M/256) = 256 blocks (full chip). LDS 48KB single-buffered
// (3 blocks/CU TLP). GROUPED-plane 3-combo windows, 64 windows of K=32.
// ---------------------------------------------------------------------------
__global__ __launch_bounds__(512)
void mgemm_outN(const unsigned short* __restrict__ A,   // [M][4096] grouped
                const unsigned short* __restrict__ B,   // [1024][4096] grouped
                float* __restrict__ C)                  // [M][1024]
{
  __shared__ __align__(16) unsigned short As[256*64];   // 32KB
  __shared__ __align__(16) unsigned short Bs[128*64];   // 16KB
  const int t = threadIdx.x;
  const int mbase = blockIdx.y << 8, nbase = blockIdx.x << 7;
  const int lane = t & 63, w = t >> 6;
  const int wr = w & 3, wc = w >> 2;            // 4 m-sub x 2 n-sub
  const int l16 = lane & 15, kq = lane >> 4;

  // staging: 512 thr, 8 per row -> 64 rows/call. A: 4 calls, B: 2 calls.
  const int sr = t >> 3, sl8 = t & 7;
  const unsigned short* pA[4]; int dA[4];
  const unsigned short* pB[2]; int dB[2];
  #pragma unroll
  for (int c=0;c<4;c++){
    int row = c*64 + sr;
    int ss  = sl8 ^ (row & 7);
    int pofs = (ss < 4) ? (ss<<3) : (256 + ((ss-4)<<3));
    pA[c] = A + (size_t)(mbase+row)*4096 + pofs;
    dA[c] = row*64 + sl8*8;
  }
  #pragma unroll
  for (int c=0;c<2;c++){
    int row = c*64 + sr;
    int ss  = sl8 ^ (row & 7);
    int pofs = (ss < 4) ? (ss<<3) : (256 + ((ss-4)<<3));
    pB[c] = B + (size_t)(nbase+row)*4096 + pofs;
    dB[c] = row*64 + sl8*8;
  }

  f32x4 acc[4][4];
  #pragma unroll
  for (int i=0;i<4;i++)
    #pragma unroll
    for (int j=0;j<4;j++) acc[i][j] = (f32x4){0.f,0.f,0.f,0.f};

  for (int i=0; i<64; i++){
    const int v = i*32;
    const int gso = ((v>>8)<<9) + (v & 255);   // 512*g + j
    #pragma unroll
    for (int c=0;c<4;c++) gld16(pA[c] + gso, &As[dA[c]]);
    #pragma unroll
    for (int c=0;c<2;c++) gld16(pB[c] + gso, &Bs[dB[c]]);
    __syncthreads();
    bf16x8 ah[4], al[4];
    #pragma unroll
    for (int mf=0; mf<4; mf++){
      int ra = wr*64 + mf*16 + l16;
      ah[mf] = *(const bf16x8*)&As[ra*64 + (( kq      ^ (ra&7))<<3)];
      al[mf] = *(const bf16x8*)&As[ra*64 + (((kq+4)   ^ (ra&7))<<3)];
    }
    #pragma unroll
    for (int nf=0; nf<4; nf++){
      int rb = wc*64 + nf*16 + l16;
      bf16x8 bh = *(const bf16x8*)&Bs[rb*64 + (( kq    ^ (rb&7))<<3)];
      bf16x8 bl = *(const bf16x8*)&Bs[rb*64 + (((kq+4) ^ (rb&7))<<3)];
      #pragma unroll
      for (int mf=0; mf<4; mf++){
        acc[mf][nf] = __builtin_amdgcn_mfma_f32_16x16x32_bf16(ah[mf], bh, acc[mf][nf], 0,0,0);
        acc[mf][nf] = __builtin_amdgcn_mfma_f32_16x16x32_bf16(ah[mf], bl, acc[mf][nf], 0,0,0);
        acc[mf][nf] = __builtin_amdgcn_mfma_f32_16x16x32_bf16(al[mf], bh, acc[mf][nf], 0,0,0);
      }
    }
    __syncthreads();
  }

  #pragma unroll
  for (int mf=0; mf<4; mf++){
    int r0 = mbase + wr*64 + mf*16 + kq*4;
    #pragma unroll
    for (int nf=0; nf<4; nf++){
      int c = nbase + wc*64 + nf*16 + l16;
      #pragma unroll
      for (int r=0;r<4;r++)
        C[(size_t)(r0+r)*1024 + c] = acc[mf][nf][r];
    }
  }
}

// ---------------------------------------------------------------------------
// x_proj GEMM, single-staged 3-combo + double-buffered counted-vmcnt (r15).
// ---------------------------------------------------------------------------
__global__ __launch_bounds__(256)
void xproj_pair(const unsigned short* __restrict__ A,   // U2 [M][4096] {h|l}
                const unsigned short* __restrict__ W2,  // [96][4096] {h|l}
                float* __restrict__ XD)
{
  __shared__ __align__(16) unsigned short S[2][128*64];
  const int t = threadIdx.x;
  const int mbase = blockIdx.x << 5;
  const int lane = t & 63, w = t >> 6;
  const int mf = w & 1, nc0 = (w >> 1) * 48;
  const int l16 = lane & 15, kq = lane >> 4;

  const unsigned short* ps[4]; int dofs[4];
  #pragma unroll
  for (int c=0;c<4;c++){
    int idx = c*256 + t;
    int row = idx >> 3, sl8 = idx & 7;
    int ss  = sl8 ^ (row & 7);
    int colb = (ss < 4) ? (ss<<3) : (2048 + ((ss-4)<<3));
    ps[c] = (row < 32) ? (A + (size_t)(mbase+row)*4096 + colb)
                       : (W2 + (size_t)(row-32)*4096 + colb);
    dofs[c] = row*64 + sl8*8;
  }

  f32x4 acc[3];
  #pragma unroll
  for (int j=0;j<3;j++) acc[j] = (f32x4){0.f,0.f,0.f,0.f};

#define STG(buf, k0) { _Pragma("unroll") \
    for (int c=0;c<4;c++) gld16(ps[c] + (k0), &S[buf][dofs[c]]); }

  STG(0, 0);
  asm volatile("s_waitcnt vmcnt(0)" ::: "memory");
  __builtin_amdgcn_s_barrier();
  __builtin_amdgcn_sched_barrier(0);

  for (int i=0; i<64; i++){
    const int cur = i & 1, nxt = cur ^ 1;
    const bool hn = (i+1 < 64);
    if (hn){
      STG(nxt, (i+1)*32);
      asm volatile("s_waitcnt vmcnt(4)" ::: "memory");
    } else {
      asm volatile("s_waitcnt vmcnt(0)" ::: "memory");
    }
    __builtin_amdgcn_s_barrier();
    __builtin_amdgcn_sched_barrier(0);

    const unsigned short* Sc = S[cur];
    int ra = mf*16 + l16;
    bf16x8 ah = *(const bf16x8*)&Sc[ra*64 + (( kq    ^ (ra&7))<<3)];
    bf16x8 al = *(const bf16x8*)&Sc[ra*64 + (((kq+4) ^ (ra&7))<<3)];
    #pragma unroll
    for (int nf=0; nf<3; nf++){
      int rb = 32 + nc0 + nf*16 + l16;
      bf16x8 bh = *(const bf16x8*)&Sc[rb*64 + (( kq    ^ (rb&7))<<3)];
      bf16x8 bl = *(const bf16x8*)&Sc[rb*64 + (((kq+4) ^ (rb&7))<<3)];
      acc[nf] = __builtin_amdgcn_mfma_f32_16x16x32_bf16(ah, bh, acc[nf], 0,0,0);
      acc[nf] = __builtin_amdgcn_mfma_f32_16x16x32_bf16(ah, bl, acc[nf], 0,0,0);
      acc[nf] = __builtin_amdgcn_mfma_f32_16x16x32_bf16(al, bh, acc[nf], 0,0,0);
    }
    __builtin_amdgcn_s_barrier();
  }
#undef STG

  #pragma unroll
  for (int nf=0; nf<3; nf++){
    int c = nc0 + nf*16 + l16;
    int r0s = mbase + mf*16 + kq*4;
    #pragma unroll
    for (int r=0;r<4;r++)
      XD[(size_t)(r0s+r)*96 + c] = acc[nf][r];
  }
}

// ---------------------------------------------------------------------------
// dt_proj MFMA (r14 proven): K=64 fully staged once, 96 MFMAs, softplus.
// ---------------------------------------------------------------------------
__global__ __launch_bounds__(256)
void mgemm_dt2(const float* __restrict__ XDf,           // [M][96], cols 0..63
               const unsigned short* __restrict__ DTW2, // [2048][128] pair
               float* __restrict__ XI,
               const float* __restrict__ dtb)
{
  __shared__ __align__(16) unsigned short As[128*128];
  __shared__ __align__(16) unsigned short Bs[128*128];
  const int t = threadIdx.x;
  const int mbase = blockIdx.y << 7, nbase = blockIdx.x << 7;
  const int lane = t & 63, w = t >> 6;
  const int wr = w >> 1, wc = w & 1;
  const int l16 = lane & 15, kq = lane >> 4;

  {
    const int row = t >> 1, half = (t & 1) << 5;
    const int r7 = row & 7;
    const float* src = XDf + (size_t)(mbase + row)*96 + half;
    #pragma unroll
    for (int i=0;i<4;i++){
      int g = (half >> 3) + i;
      CV8P(&As[row*128 + ((g ^ r7)<<3)], src + i*8);
    }
  }
  {
    #pragma unroll
    for (int q=0;q<8;q++){
      int idx = q*256 + t;
      int row = idx >> 4, sl = idx & 15;
      int ss  = (sl & 8) | ((sl & 7) ^ (row & 7));
      int col = (ss < 8) ? (ss<<3) : (64 + ((ss-8)<<3));
      gld16(DTW2 + (size_t)(nbase+row)*128 + col, &Bs[row*128 + sl*8]);
    }
  }
  __syncthreads();

  f32x4 acc[4][4];
  #pragma unroll
  for (int i=0;i<4;i++)
    #pragma unroll
    for (int j=0;j<4;j++) acc[i][j] = (f32x4){0.f,0.f,0.f,0.f};

  #pragma unroll
  for (int kb=0; kb<3; kb++){
    const int aoff = (kb==2) ? 8 : 0;
    const int boff = (kb==1) ? 8 : 0;
    #pragma unroll
    for (int kw=0; kw<2; kw++){
      const int sbase = kw*4 + kq;
      bf16x8 af[4];
      #pragma unroll
      for (int mf=0; mf<4; mf++){
        int ra = wr*64 + mf*16 + l16;
        int sA = ((sbase ^ (ra&7)) + aoff);
        af[mf] = *(const bf16x8*)&As[ra*128 + (sA<<3)];
      }
      #pragma unroll
      for (int nf=0; nf<4; nf++){
        int rb = wc*64 + nf*16 + l16;
        int sB = ((sbase ^ (rb&7)) + boff);
        bf16x8 bfr = *(const bf16x8*)&Bs[rb*128 + (sB<<3)];
        #pragma unroll
        for (int mf=0; mf<4; mf++)
          acc[mf][nf] = __builtin_amdgcn_mfma_f32_16x16x32_bf16(af[mf], bfr, acc[mf][nf], 0,0,0);
      }
    }
  }

  #pragma unroll
  for (int mf=0; mf<4; mf++){
    int r0 = mbase + wr*64 + mf*16 + kq*4;
    #pragma unroll
    for (int nf=0; nf<4; nf++){
      int c = nbase + wc*64 + nf*16 + l16;
      float eb = dtb[c];
      #pragma unroll
      for (int r=0;r<4;r++)
        XI[(size_t)(r0+r)*2048 + c] = softplusf(acc[mf][nf][r] + eb);
    }
  }
}

// ---------------------------------------------------------------------------
// Causal depthwise conv (k=4) + bias + SiLU: 4 rows x 8 d per thread (r14).
// ---------------------------------------------------------------------------
__global__ __launch_bounds__(256)
void conv_silu4(const float* __restrict__ xi, const float* __restrict__ cw,
                const float* __restrict__ cb, unsigned short* __restrict__ u2)
{
  const int r0 = blockIdx.x << 2;
  const int d0 = threadIdx.x << 3;
  const int tt0 = r0 & (SEQL-1);

  float wk[4][8];
  {
    const float4* cw4 = (const float4*)(cw + (size_t)d0*4);
    #pragma unroll
    for (int j=0;j<8;j++){
      float4 wj = cw4[j];
      wk[0][j]=wj.x; wk[1][j]=wj.y; wk[2][j]=wj.z; wk[3][j]=wj.w;
    }
  }
  float bias[8];
  *(float4*)&bias[0] = *(const float4*)(cb + d0);
  *(float4*)&bias[4] = *(const float4*)(cb + d0 + 4);

  float v[7][8];
#define LD8(dst, p) { *(float4*)&dst[0] = ((const float4*)(p))[0]; \
                      *(float4*)&dst[4] = ((const float4*)(p))[1]; }
  #pragma unroll
  for (int k=0;k<7;k++){
    int trel = tt0 - 3 + k;
    if (trel >= 0){
      LD8(v[k], xi + (size_t)(r0 - 3 + k)*DINNER + d0);
    } else {
      #pragma unroll
      for (int j=0;j<8;j++) v[k][j] = 0.f;
    }
  }
#undef LD8

  #pragma unroll
  for (int jrow=0; jrow<4; jrow++){
    unsigned short h8[8], l8[8];
    #pragma unroll
    for (int j=0;j<8;j++){
      float y = fmaf(v[jrow+3][j], wk[3][j], fmaf(v[jrow+2][j], wk[2][j],
                fmaf(v[jrow+1][j], wk[1][j], fmaf(v[jrow][j], wk[0][j], bias[j]))));
      float uv = siluf(y);
      split_bf(uv, h8[j], l8[j]);
    }
    unsigned short* outp = u2 + (size_t)(r0 + jrow)*4096 + d0;
    *(uint4*)outp          = *(const uint4*)h8;
    *(uint4*)(outp + 2048) = *(const uint4*)l8;
  }
}

// ---------------------------------------------------------------------------
// Chunked selective scan, PIPELINED double-buffer (r12 proven, unchanged).
// ---------------------------------------------------------------------------
template<int PASS>
__global__ __launch_bounds__(256)
void scan_chunk(const unsigned short* __restrict__ u2, float* __restrict__ dty,
                const float* __restrict__ xdbl, const float* __restrict__ zb,
                const float* __restrict__ A_log, const float* __restrict__ Dp,
                float* __restrict__ hfin, float* __restrict__ sumdt)
{
  __shared__ __align__(16) float Tdt[2][TT][256];
  __shared__ __align__(16) float Tu [2][TT][256];
  __shared__ __align__(16) float Tz [(PASS==3)?2:1][(PASS==3)?TT:1][(PASS==3)?256:4];
  __shared__ __align__(16) float Tbc[2][TT][32];

  const int tid = threadIdx.x;
  const int idx = blockIdx.x*256 + tid;
  const int d = idx & (DINNER-1);
  const int g = idx >> 11;          // uniform per block
  const int cck = g & (NC-1);
  const int bb = g >> 5;
  const int wv = tid >> 6, ln = tid & 63;
  const int dbase = (blockIdx.x << 8) & (DINNER-1);

  float A2[16];
  {
    const float* al = A_log + (size_t)d*DSTATE;
    #pragma unroll
    for (int s=0;s<16;s++) A2[s] = -expf(al[s]) * 1.44269504f;
  }
  float h[16];
  if (PASS == 1){
    #pragma unroll
    for (int s=0;s<16;s++) h[s] = 0.f;
  } else {
    const float* hp = hfin + ((size_t)g*DINNER + d)*16;
    #pragma unroll
    for (int s=0;s<16;s+=4) *(float4*)&h[s] = *(const float4*)(hp + s);
  }
  const float Dv = (PASS==3) ? Dp[d] : 0.f;

  const size_t row0 = (size_t)bb*SEQL + (size_t)cck*TC;

#define STAGE(buf, T0) do { \
    _Pragma("unroll") \
    for (int q=0;q<2;q++){ \
      int r = q*4 + wv; \
      size_t rowi = row0 + (T0) + r; \
      gld16(dty + rowi*2048 + dbase + ln*4, &Tdt[buf][r][0]); \
      const unsigned short* us = u2 + rowi*4096 + \
          ((ln < 32) ? (dbase + ln*8) : (2048 + dbase + (ln-32)*8)); \
      gld16(us, &Tu[buf][r][0]); \
      if (PASS==3) gld16(zb + rowi*2048 + dbase + ln*4, &Tz[buf][r][0]); \
    } \
    if (wv == 3){ \
      gld16(xdbl + (row0 + (T0) + (ln>>3))*96 + 64 + (ln&7)*4, &Tbc[buf][0][0]); \
    } \
  } while(0)

  STAGE(0, 0);
  asm volatile("s_waitcnt vmcnt(0)" ::: "memory");
  __builtin_amdgcn_s_barrier();
  __builtin_amdgcn_sched_barrier(0);

  float sdt = 0.f;

  for (int t0 = 0; t0 < TC; t0 += TT){
    const int cur = (t0 >> 3) & 1, nxt = cur ^ 1;
    const bool hasNext = (t0 + TT < TC);
    if (hasNext) STAGE(nxt, t0 + TT);

    if (hasNext){
      if (PASS==3){
        if (wv==3) asm volatile("s_waitcnt vmcnt(7)" ::: "memory");
        else       asm volatile("s_waitcnt vmcnt(6)" ::: "memory");
      } else {
        if (wv==3) asm volatile("s_waitcnt vmcnt(5)" ::: "memory");
        else       asm volatile("s_waitcnt vmcnt(4)" ::: "memory");
      }
    } else {
      asm volatile("s_waitcnt vmcnt(0)" ::: "memory");
    }
    __builtin_amdgcn_s_barrier();
    __builtin_amdgcn_sched_barrier(0);

    #pragma unroll
    for (int tt=0; tt<TT; tt++){
      float dtc = Tdt[cur][tt][tid];
      const unsigned short* tur = (const unsigned short*)&Tu[cur][tt][0];
      float uc = __uint_as_float((u32)tur[tid] << 16)
               + __uint_as_float((u32)tur[256+tid] << 16);
      float Bv[16], Cv[16];
      #pragma unroll
      for (int q=0;q<4;q++) *(float4*)&Bv[q*4] = *(const float4*)&Tbc[cur][tt][q*4];
      if (PASS==3){
        #pragma unroll
        for (int q=0;q<4;q++) *(float4*)&Cv[q*4] = *(const float4*)&Tbc[cur][tt][16+q*4];
      }
      if (PASS==1) sdt += dtc;
      float du = dtc*uc;
      float y = 0.f;
      #pragma unroll
      for (int s=0;s<16;s++){
        float dA = exp2f(dtc*A2[s]);
        h[s] = fmaf(dA, h[s], du*Bv[s]);
        if (PASS==3) y = fmaf(h[s], Cv[s], y);
      }
      if (PASS==3){
        float zc = Tz[cur][tt][tid];
        y = fmaf(uc, Dv, y);
        float gv = y * siluf(zc);
        unsigned short gh, gl;
        split_bf(gv, gh, gl);
        Tdt[cur][tt][tid] = __uint_as_float((u32)gh | ((u32)gl << 16));
      }
    }

    if (PASS==3) asm volatile("s_waitcnt lgkmcnt(0)" ::: "memory");
    __builtin_amdgcn_s_barrier();
    __builtin_amdgcn_sched_barrier(0);

    if (PASS==3){
      #pragma unroll
      for (int q=0;q<2;q++){
        int r = q*4 + wv;
        size_t rowi = row0 + t0 + r;
        const u32* T = (const u32*)&Tdt[cur][r][0];
        int o0 = ln*4;
        u32 vals[4];
        if (ln < 32){
          #pragma unroll
          for (int k=0;k<4;k++){
            int i2 = (o0+k)*2;
            vals[k] = (T[i2] & 0xFFFFu) | (T[i2+1] << 16);
          }
        } else {
          #pragma unroll
          for (int k=0;k<4;k++){
            int i2 = (o0+k-128)*2;
            vals[k] = (T[i2] >> 16) | (T[i2+1] & 0xFFFF0000u);
          }
        }
        *(float4*)(dty + rowi*2048 + dbase + o0) = *(const float4*)vals;
      }
    }
  }
#undef STAGE

  if (PASS==1){
    float* hp = hfin + ((size_t)g*DINNER + d)*16;
    #pragma unroll
    for (int s=0;s<16;s+=4) *(float4*)(hp + s) = *(const float4*)&h[s];
    sumdt[(size_t)g*DINNER + d] = sdt;
  }
}

// ---------------------------------------------------------------------------
// Propagate chunk-initial states: in-place hfin[c] := H_init(c).
// ---------------------------------------------------------------------------
__global__ __launch_bounds__(256)
void scan_prop(const float* __restrict__ A_log, float* __restrict__ hfin,
               const float* __restrict__ sumdt)
{
  int idx = blockIdx.x*256 + threadIdx.x;
  int s = idx & 15;
  int d = (idx >> 4) & (DINNER-1);
  int b = idx >> 15;
  float A2 = -expf(A_log[(size_t)d*DSTATE + s]) * 1.44269504f;
  float H = 0.f;
  size_t hbase = ((size_t)b*NC*DINNER + d)*16 + s;
  size_t sbase = (size_t)b*NC*DINNER + d;
  for (int c=0;c<NC;c++){
    float P   = exp2f(A2 * sumdt[sbase + (size_t)c*DINNER]);
    float tmp = hfin[hbase + (size_t)c*DINNER*16];
    hfin[hbase + (size_t)c*DINNER*16] = H;
    H = fmaf(P, H, tmp);
  }
}

// ---------------------------------------------------------------------------
// Launcher.  Fixed (52.95 MB): INW2 33.55 + OUTWG 16.78 + XPW2 1.57 +
// DTW2 1.05.  Per batch (58.72 MB).  NB=4 -> 287.8 MB (< 305.1 known-good).
// ---------------------------------------------------------------------------
extern "C" void kernel_launch(void* const* d_in, const int* in_sizes, int n_in,
                              void* d_out, int out_size, void* d_ws, size_t ws_size,
                              hipStream_t stream)
{
  const float* x    = (const float*)d_in[0];
  const float* in_w = (const float*)d_in[1];
  const float* cw   = (const float*)d_in[2];
  const float* cb   = (const float*)d_in[3];
  const float* xpw  = (const float*)d_in[4];
  const float* dtw  = (const float*)d_in[5];
  const float* dtb  = (const float*)d_in[6];
  const float* A_log= (const float*)d_in[7];
  const float* Dp   = (const float*)d_in[8];
  const float* ow   = (const float*)d_in[9];
  const float* nw   = (const float*)d_in[10];
  const float* nb   = (const float*)d_in[11];
  float* outF = (float*)d_out;

  const size_t fixedB = 33554432ULL + 16777216ULL + 1572864ULL + 1048576ULL;
  const size_t perB   = 58720256ULL;
  int NB = 4;
  while (NB > 1 && fixedB + (size_t)NB*perB > ws_size) NB >>= 1;
  const int Mc = NB * SEQL;
  const int nchunk = SEQB / NB;

  unsigned short* INW2  = (unsigned short*)d_ws;                 // [2][4096][2048]
  unsigned short* OUTWG = INW2 + (size_t)2*4096*2048;            // [2][1024][4096]
  unsigned short* XPW2  = OUTWG + (size_t)2*1024*4096;           // [2][96][4096]
  unsigned short* DTW2  = XPW2 + (size_t)2*96*4096;              // [2][2048][128]
  char* dyn = (char*)(DTW2 + (size_t)2*2048*128);

  unsigned short* SH = (unsigned short*)dyn;                     // Mc*2048 ushort
  float* XD = (float*)dyn;                                       // Mc*96  (alias SH)
  float* HF = (float*)(dyn + (size_t)Mc*384);                    // Mc*512 (alias SH)
  float* SD = (float*)(dyn + (size_t)Mc*2432);                   // Mc*32  (alias SH)
  float* XI = (float*)(dyn + (size_t)Mc*4096);                   // Mc*2048 f32
  float* ZB = XI + (size_t)Mc*2048;                              // Mc*2048
  unsigned short* U2 = (unsigned short*)(ZB + (size_t)Mc*2048);  // Mc*4096 ushort

  // Weight pre-splits
  wsplit2<<<8192, 256, 0, stream>>>(in_w, INW2, 1024, 8);
  wsplit2<<<384,  256, 0, stream>>>(xpw,  XPW2, 2048, 9);
  wsplit2<<<256,  256, 0, stream>>>(dtw,  DTW2, 64, 4);
  wsplit_og<<<4096, 256, 0, stream>>>(ow, OUTWG);

  for (int c = 0; c < nchunk; ++c){
    const size_t rowoff = (size_t)c * Mc;
    const float* xrows = x + rowoff * DMODEL;
    float* X1 = outF + rowoff * DMODEL;     // layer-0 out / final out rows

    for (int l = 0; l < 2; ++l){
      const float* Al = A_log + (size_t)l*DINNER*DSTATE;

      // 1. LayerNorm (+ residual for layer 1) -> SH pair
      ln_split2<<<Mc, 256, 0, stream>>>(
          (l==0) ? xrows : X1, (l==0) ? nullptr : xrows,
          nw + (size_t)l*DMODEL, nb + (size_t)l*DMODEL, SH);

      // 2. in_proj fused xi|z (256x256 8-wave, single-buf): -> XI / ZB
      mgemm_in8<<<dim3(16, Mc/256), 512, 0, stream>>>(
          SH, INW2 + (size_t)l*4096*2048, XI, ZB);

      // 3. causal conv + bias + SiLU: XI -> U2 (split pair), 4-row threads
      conv_silu4<<<Mc/4, 256, 0, stream>>>(
          XI, cw + (size_t)l*DINNER*4, cb + (size_t)l*DINNER, U2);

      // 4. x_proj (pipelined pair GEMM) -> XD
      xproj_pair<<<Mc/32, 256, 0, stream>>>(
          U2, XPW2 + (size_t)l*96*4096, XD);

      // 5. dt_proj MFMA + bias + softplus -> XI (xi dead after conv)
      mgemm_dt2<<<dim3(16, Mc/128), 256, 0, stream>>>(
          XD, DTW2 + (size_t)l*2048*128, XI, dtb + (size_t)l*DINNER);

      // 6. chunked scan (pipelined); pass 3 writes grouped-plane gy over XI
      scan_chunk<1><<<NB*NC*8, 256, 0, stream>>>(
          U2, XI, XD, ZB, Al, Dp + (size_t)l*DINNER, HF, SD);
      scan_prop<<<NB*128, 256, 0, stream>>>(Al, HF, SD);
      scan_chunk<3><<<NB*NC*8, 256, 0, stream>>>(
          U2, XI, XD, ZB, Al, Dp + (size_t)l*DINNER, HF, SD);

      // 7. out_proj (256x128 tile, 256 blocks, single-buf): -> X1 rows
      mgemm_outN<<<dim3(8, Mc/256), 512, 0, stream>>>(
          (const unsigned short*)XI, OUTWG + (size_t)l*1024*4096, X1);
    }
  }
}

// Round 19
// 2994.001 us; speedup vs baseline: 1.0979x; 1.0492x over previous
//
#include <hip/hip_runtime.h>
#include <cstddef>
#include <cstdint>

// Problem constants (from reference)
#define SEQB   8
#define SEQL   2048
#define DMODEL 1024
#define DINNER 2048
#define DSTATE 16
#define NC     32            // scan chunks along t
#define TC     64            // SEQL/NC
#define TT     8             // scan LDS tile rows (t per stage)

typedef __attribute__((ext_vector_type(4))) float f32x4;
typedef __attribute__((ext_vector_type(8))) short bf16x8;
typedef unsigned int u32;
typedef const __attribute__((address_space(1))) u32* gas_ptr;
typedef __attribute__((address_space(3))) u32* las_ptr;

__device__ __forceinline__ void gld16(const void* g, void* l){
  __builtin_amdgcn_global_load_lds((gas_ptr)g, (las_ptr)l, 16, 0, 0);
}

__device__ __forceinline__ float siluf(float x){ return x / (1.f + __expf(-x)); }
__device__ __forceinline__ float softplusf(float x){ return (x > 20.f) ? x : log1pf(__expf(x)); }

// RNE fp32 -> bf16 bits
__device__ __forceinline__ unsigned short f2bf_rne(float f){
  unsigned int u = __float_as_uint(f);
  u += 0x7FFFu + ((u>>16)&1u);
  return (unsigned short)(u>>16);
}
__device__ __forceinline__ void split_bf(float f, unsigned short& h, unsigned short& l){
  unsigned short hs = f2bf_rne(f);
  float hf = __uint_as_float(((unsigned int)hs)<<16);
  h = hs;
  l = f2bf_rne(f - hf);
}

// Convert 8 consecutive fp32 at PSRC into hi/lo bf16x8; store to PH / PH+64.
#define CV8P(PH, PSRC) { \
  const float4* _p4 = (const float4*)(PSRC); \
  float4 _a = _p4[0], _b = _p4[1]; \
  bf16x8 _H, _L; unsigned short _h,_l; \
  split_bf(_a.x,_h,_l); _H[0]=(short)_h; _L[0]=(short)_l; \
  split_bf(_a.y,_h,_l); _H[1]=(short)_h; _L[1]=(short)_l; \
  split_bf(_a.z,_h,_l); _H[2]=(short)_h; _L[2]=(short)_l; \
  split_bf(_a.w,_h,_l); _H[3]=(short)_h; _L[3]=(short)_l; \
  split_bf(_b.x,_h,_l); _H[4]=(short)_h; _L[4]=(short)_l; \
  split_bf(_b.y,_h,_l); _H[5]=(short)_h; _L[5]=(short)_l; \
  split_bf(_b.z,_h,_l); _H[6]=(short)_h; _L[6]=(short)_l; \
  split_bf(_b.w,_h,_l); _H[7]=(short)_h; _L[7]=(short)_l; \
  *(bf16x8*)(PH) = _H; *(bf16x8*)((unsigned short*)(PH) + 64) = _L; }

// ---------------------------------------------------------------------------
// Weight pre-split PAIR {h|l}: src [R][K] fp32 -> dst [R][2K] bf16.
// ---------------------------------------------------------------------------
__global__ __launch_bounds__(256)
void wsplit2(const float* __restrict__ src, unsigned short* __restrict__ dst,
             int K, int k4shift)
{
  int idx = blockIdx.x*256 + threadIdx.x;
  int r  = idx >> k4shift;
  int c4 = idx & ((1<<k4shift)-1);
  float4 v = ((const float4*)src)[idx];
  unsigned short h,l; short4 h4, l4;
  split_bf(v.x,h,l); h4.x=(short)h; l4.x=(short)l;
  split_bf(v.y,h,l); h4.y=(short)h; l4.y=(short)l;
  split_bf(v.z,h,l); h4.z=(short)h; l4.z=(short)l;
  split_bf(v.w,h,l); h4.w=(short)h; l4.w=(short)l;
  size_t ro = (size_t)r*2*K;
  *(short4*)&dst[ro + (c4<<2)]     = h4;
  *(short4*)&dst[ro + K + (c4<<2)] = l4;
}

// ---------------------------------------------------------------------------
// out_proj weight split, GROUPED pair layout matching scan's gy write.
// ---------------------------------------------------------------------------
__global__ __launch_bounds__(256)
void wsplit_og(const float* __restrict__ src, unsigned short* __restrict__ dst)
{
  int idx = blockIdx.x*256 + threadIdx.x;
  int r  = idx >> 9;
  int c4 = idx & 511;
  int layer = r >> 10, rr = r & 1023;
  float4 v = ((const float4*)src)[idx];
  unsigned short h,l; short4 h4, l4;
  split_bf(v.x,h,l); h4.x=(short)h; l4.x=(short)l;
  split_bf(v.y,h,l); h4.y=(short)h; l4.y=(short)l;
  split_bf(v.z,h,l); h4.z=(short)h; l4.z=(short)l;
  split_bf(v.w,h,l); h4.w=(short)h; l4.w=(short)l;
  int col = c4 << 2;
  int g = col >> 8, j = col & 255;
  size_t base = (size_t)layer*1024*4096 + (size_t)rr*4096 + g*512 + j;
  *(short4*)&dst[base]       = h4;
  *(short4*)&dst[base + 256] = l4;
}

// ---------------------------------------------------------------------------
// LayerNorm (+ optional residual) fused with PAIR split {h|l}.
// ---------------------------------------------------------------------------
__global__ __launch_bounds__(256)
void ln_split2(const float* __restrict__ a, const float* __restrict__ res,
               const float* __restrict__ w, const float* __restrict__ bias,
               unsigned short* __restrict__ Hs)
{
  int row = blockIdx.x;
  size_t off = (size_t)row * DMODEL;
  float4 v = ((const float4*)(a + off))[threadIdx.x];
  if (res){
    float4 u = ((const float4*)(res + off))[threadIdx.x];
    v.x += u.x; v.y += u.y; v.z += u.z; v.w += u.w;
  }
  float s  = v.x + v.y + v.z + v.w;
  float s2 = fmaf(v.x,v.x, fmaf(v.y,v.y, fmaf(v.z,v.z, v.w*v.w)));
  #pragma unroll
  for (int o=32;o>0;o>>=1){ s += __shfl_down(s,o,64); s2 += __shfl_down(s2,o,64); }
  __shared__ float red[8];
  int lane = threadIdx.x & 63, wid = threadIdx.x >> 6;
  if (lane==0){ red[wid]=s; red[4+wid]=s2; }
  __syncthreads();
  s  = red[0]+red[1]+red[2]+red[3];
  s2 = red[4]+red[5]+red[6]+red[7];
  float mu  = s * (1.f/DMODEL);
  float var = s2 * (1.f/DMODEL) - mu*mu;
  float rstd = rsqrtf(var + 1e-5f);
  float4 wv = ((const float4*)w)[threadIdx.x];
  float4 bv = ((const float4*)bias)[threadIdx.x];
  float4 o4;
  o4.x = (v.x-mu)*rstd*wv.x + bv.x;
  o4.y = (v.y-mu)*rstd*wv.y + bv.y;
  o4.z = (v.z-mu)*rstd*wv.z + bv.z;
  o4.w = (v.w-mu)*rstd*wv.w + bv.w;
  unsigned short h,l; short4 h4, l4;
  split_bf(o4.x,h,l); h4.x=(short)h; l4.x=(short)l;
  split_bf(o4.y,h,l); h4.y=(short)h; l4.y=(short)l;
  split_bf(o4.z,h,l); h4.z=(short)h; l4.z=(short)l;
  split_bf(o4.w,h,l); h4.w=(short)h; l4.w=(short)l;
  size_t ro = (size_t)row*2048;
  int c = threadIdx.x<<2;
  *(short4*)&Hs[ro + c]        = h4;
  *(short4*)&Hs[ro + 1024 + c] = l4;
}

// ---------------------------------------------------------------------------
// in_proj GEMM, 256x256 tile, 8 waves (512 thr), wave tile 64x128.
// Single-staged 3-combo windows; LDS = 64KB (2 blocks/CU TLP). r16-proven.
// Epilogue: bx<8 -> XI, else -> ZB. M mult of 256.
// ---------------------------------------------------------------------------
__global__ __launch_bounds__(512)
void mgemm_in8(const unsigned short* __restrict__ A,   // [M][2048] {h|l}
               const unsigned short* __restrict__ B,   // [4096][2048] {h|l}
               float* __restrict__ XI, float* __restrict__ ZB)
{
  __shared__ __align__(16) unsigned short As[256*64];
  __shared__ __align__(16) unsigned short Bs[256*64];
  const int t = threadIdx.x;
  const int mbase = blockIdx.y << 8, nbase = blockIdx.x << 8;
  const int lane = t & 63, w = t >> 6;          // 8 waves
  const int wr = w & 3, wc = w >> 2;            // 4x2 wave grid
  const int l16 = lane & 15, kq = lane >> 4;

  const int sr8 = lane >> 3, sl8 = lane & 7;
  const unsigned short* pA[4]; const unsigned short* pB[4];
  int dofs[4];
  #pragma unroll
  for (int c=0;c<4;c++){
    int row = w*32 + c*8 + sr8;                 // 0..255
    int ss  = sl8 ^ (row & 7);
    int colb = (ss < 4) ? (ss<<3) : (1024 + ((ss-4)<<3));
    pA[c] = A + (size_t)(mbase+row)*2048 + colb;
    pB[c] = B + (size_t)(nbase+row)*2048 + colb;
    dofs[c] = row*64 + sl8*8;
  }

  f32x4 acc[4][8];
  #pragma unroll
  for (int i=0;i<4;i++)
    #pragma unroll
    for (int j=0;j<8;j++) acc[i][j] = (f32x4){0.f,0.f,0.f,0.f};

  for (int k0=0; k0<1024; k0+=32){
    #pragma unroll
    for (int c=0;c<4;c++){
      gld16(pA[c] + k0, &As[dofs[c]]);
      gld16(pB[c] + k0, &Bs[dofs[c]]);
    }
    __syncthreads();
    bf16x8 ah[4], al[4];
    #pragma unroll
    for (int mf=0; mf<4; mf++){
      int ra = wr*64 + mf*16 + l16;
      ah[mf] = *(const bf16x8*)&As[ra*64 + (( kq      ^ (ra&7))<<3)];
      al[mf] = *(const bf16x8*)&As[ra*64 + (((kq+4)   ^ (ra&7))<<3)];
    }
    #pragma unroll
    for (int nf=0; nf<8; nf++){
      int rb = wc*128 + nf*16 + l16;
      bf16x8 bh = *(const bf16x8*)&Bs[rb*64 + (( kq    ^ (rb&7))<<3)];
      bf16x8 bl = *(const bf16x8*)&Bs[rb*64 + (((kq+4) ^ (rb&7))<<3)];
      #pragma unroll
      for (int mf=0; mf<4; mf++){
        acc[mf][nf] = __builtin_amdgcn_mfma_f32_16x16x32_bf16(ah[mf], bh, acc[mf][nf], 0,0,0);
        acc[mf][nf] = __builtin_amdgcn_mfma_f32_16x16x32_bf16(ah[mf], bl, acc[mf][nf], 0,0,0);
        acc[mf][nf] = __builtin_amdgcn_mfma_f32_16x16x32_bf16(al[mf], bh, acc[mf][nf], 0,0,0);
      }
    }
    __syncthreads();
  }

  float* Cd = (nbase < 2048) ? XI : ZB;
  const int cb = (nbase < 2048) ? nbase : (nbase - 2048);
  #pragma unroll
  for (int mf=0; mf<4; mf++){
    int r0 = mbase + wr*64 + mf*16 + kq*4;
    #pragma unroll
    for (int nf=0; nf<8; nf++){
      int c = cb + wc*128 + nf*16 + l16;
      #pragma unroll
      for (int r=0;r<4;r++)
        Cd[(size_t)(r0+r)*2048 + c] = acc[mf][nf][r];
    }
  }
}

// ---------------------------------------------------------------------------
// out_proj GEMM, 128x128, single-staged 3-combo GROUPED planes + dbuf
// counted-vmcnt (r15/r16 proven, ~105us). 64 windows.
// ---------------------------------------------------------------------------
__global__ __launch_bounds__(256)
void mgemm_out3(const unsigned short* __restrict__ A,   // [M][4096] grouped
                const unsigned short* __restrict__ B,   // [1024][4096] grouped
                float* __restrict__ C)                  // [M][1024]
{
  __shared__ __align__(16) unsigned short As[2][128*64];
  __shared__ __align__(16) unsigned short Bs[2][128*64];
  const int t = threadIdx.x;
  const int mbase = blockIdx.y << 7, nbase = blockIdx.x << 7;

  const int lane = t & 63, w = t >> 6;
  const int wr = w >> 1, wc = w & 1;
  const int l16 = lane & 15, kq = lane >> 4;

  const int sr8 = lane >> 3, sl8 = lane & 7;
  const unsigned short* pA[4]; const unsigned short* pB[4];
  int dofs[4];
  #pragma unroll
  for (int c=0;c<4;c++){
    int row = c*32 + w*8 + sr8;
    int ss  = sl8 ^ (row & 7);
    int pofs = (ss < 4) ? (ss<<3) : (256 + ((ss-4)<<3));
    pA[c] = A + (size_t)(mbase+row)*4096 + pofs;
    pB[c] = B + (size_t)(nbase+row)*4096 + pofs;
    dofs[c] = row*64 + sl8*8;
  }

  f32x4 acc[4][4];
  #pragma unroll
  for (int i=0;i<4;i++)
    #pragma unroll
    for (int j=0;j<4;j++) acc[i][j] = (f32x4){0.f,0.f,0.f,0.f};

#define GSO(i) ((((i)*32)>>8)<<9) + (((i)*32) & 255)
#define STG(buf, i) { const int gso = GSO(i); _Pragma("unroll") \
    for (int c=0;c<4;c++){ \
      gld16(pA[c] + gso, &As[buf][dofs[c]]); \
      gld16(pB[c] + gso, &Bs[buf][dofs[c]]); \
    } }

  STG(0, 0);
  asm volatile("s_waitcnt vmcnt(0)" ::: "memory");
  __builtin_amdgcn_s_barrier();
  __builtin_amdgcn_sched_barrier(0);

  for (int i=0; i<64; i++){
    const int cur = i & 1, nxt = cur ^ 1;
    const bool hn = (i+1 < 64);
    if (hn){
      STG(nxt, i+1);
      asm volatile("s_waitcnt vmcnt(8)" ::: "memory");
    } else {
      asm volatile("s_waitcnt vmcnt(0)" ::: "memory");
    }
    __builtin_amdgcn_s_barrier();
    __builtin_amdgcn_sched_barrier(0);

    const unsigned short* Ac = As[cur];
    const unsigned short* Bc = Bs[cur];
    bf16x8 ah[4], al[4];
    #pragma unroll
    for (int mf=0; mf<4; mf++){
      int ra = wr*64 + mf*16 + l16;
      ah[mf] = *(const bf16x8*)&Ac[ra*64 + (( kq      ^ (ra&7))<<3)];
      al[mf] = *(const bf16x8*)&Ac[ra*64 + (((kq+4)   ^ (ra&7))<<3)];
    }
    #pragma unroll
    for (int nf=0; nf<4; nf++){
      int rb = wc*64 + nf*16 + l16;
      bf16x8 bh = *(const bf16x8*)&Bc[rb*64 + (( kq    ^ (rb&7))<<3)];
      bf16x8 bl = *(const bf16x8*)&Bc[rb*64 + (((kq+4) ^ (rb&7))<<3)];
      #pragma unroll
      for (int mf=0; mf<4; mf++){
        acc[mf][nf] = __builtin_amdgcn_mfma_f32_16x16x32_bf16(ah[mf], bh, acc[mf][nf], 0,0,0);
        acc[mf][nf] = __builtin_amdgcn_mfma_f32_16x16x32_bf16(ah[mf], bl, acc[mf][nf], 0,0,0);
        acc[mf][nf] = __builtin_amdgcn_mfma_f32_16x16x32_bf16(al[mf], bh, acc[mf][nf], 0,0,0);
      }
    }
    __builtin_amdgcn_s_barrier();
  }
#undef STG
#undef GSO

  #pragma unroll
  for (int mf=0; mf<4; mf++){
    int r0 = mbase + wr*64 + mf*16 + kq*4;
    #pragma unroll
    for (int nf=0; nf<4; nf++){
      int c = nbase + wc*64 + nf*16 + l16;
      #pragma unroll
      for (int r=0;r<4;r++)
        C[(size_t)(r0+r)*1024 + c] = acc[mf][nf][r];
    }
  }
}

// ---------------------------------------------------------------------------
// x_proj GEMM, single-staged 3-combo + double-buffered counted-vmcnt (r15).
// ---------------------------------------------------------------------------
__global__ __launch_bounds__(256)
void xproj_pair(const unsigned short* __restrict__ A,   // U2 [M][4096] {h|l}
                const unsigned short* __restrict__ W2,  // [96][4096] {h|l}
                float* __restrict__ XD)
{
  __shared__ __align__(16) unsigned short S[2][128*64];
  const int t = threadIdx.x;
  const int mbase = blockIdx.x << 5;
  const int lane = t & 63, w = t >> 6;
  const int mf = w & 1, nc0 = (w >> 1) * 48;
  const int l16 = lane & 15, kq = lane >> 4;

  const unsigned short* ps[4]; int dofs[4];
  #pragma unroll
  for (int c=0;c<4;c++){
    int idx = c*256 + t;
    int row = idx >> 3, sl8 = idx & 7;
    int ss  = sl8 ^ (row & 7);
    int colb = (ss < 4) ? (ss<<3) : (2048 + ((ss-4)<<3));
    ps[c] = (row < 32) ? (A + (size_t)(mbase+row)*4096 + colb)
                       : (W2 + (size_t)(row-32)*4096 + colb);
    dofs[c] = row*64 + sl8*8;
  }

  f32x4 acc[3];
  #pragma unroll
  for (int j=0;j<3;j++) acc[j] = (f32x4){0.f,0.f,0.f,0.f};

#define STG(buf, k0) { _Pragma("unroll") \
    for (int c=0;c<4;c++) gld16(ps[c] + (k0), &S[buf][dofs[c]]); }

  STG(0, 0);
  asm volatile("s_waitcnt vmcnt(0)" ::: "memory");
  __builtin_amdgcn_s_barrier();
  __builtin_amdgcn_sched_barrier(0);

  for (int i=0; i<64; i++){
    const int cur = i & 1, nxt = cur ^ 1;
    const bool hn = (i+1 < 64);
    if (hn){
      STG(nxt, (i+1)*32);
      asm volatile("s_waitcnt vmcnt(4)" ::: "memory");
    } else {
      asm volatile("s_waitcnt vmcnt(0)" ::: "memory");
    }
    __builtin_amdgcn_s_barrier();
    __builtin_amdgcn_sched_barrier(0);

    const unsigned short* Sc = S[cur];
    int ra = mf*16 + l16;
    bf16x8 ah = *(const bf16x8*)&Sc[ra*64 + (( kq    ^ (ra&7))<<3)];
    bf16x8 al = *(const bf16x8*)&Sc[ra*64 + (((kq+4) ^ (ra&7))<<3)];
    #pragma unroll
    for (int nf=0; nf<3; nf++){
      int rb = 32 + nc0 + nf*16 + l16;
      bf16x8 bh = *(const bf16x8*)&Sc[rb*64 + (( kq    ^ (rb&7))<<3)];
      bf16x8 bl = *(const bf16x8*)&Sc[rb*64 + (((kq+4) ^ (rb&7))<<3)];
      acc[nf] = __builtin_amdgcn_mfma_f32_16x16x32_bf16(ah, bh, acc[nf], 0,0,0);
      acc[nf] = __builtin_amdgcn_mfma_f32_16x16x32_bf16(ah, bl, acc[nf], 0,0,0);
      acc[nf] = __builtin_amdgcn_mfma_f32_16x16x32_bf16(al, bh, acc[nf], 0,0,0);
    }
    __builtin_amdgcn_s_barrier();
  }
#undef STG

  #pragma unroll
  for (int nf=0; nf<3; nf++){
    int c = nc0 + nf*16 + l16;
    int r0s = mbase + mf*16 + kq*4;
    #pragma unroll
    for (int r=0;r<4;r++)
      XD[(size_t)(r0s+r)*96 + c] = acc[nf][r];
  }
}

// ---------------------------------------------------------------------------
// dt_proj MFMA (r14 proven): K=64 fully staged once, 96 MFMAs, softplus.
// ---------------------------------------------------------------------------
__global__ __launch_bounds__(256)
void mgemm_dt2(const float* __restrict__ XDf,           // [M][96], cols 0..63
               const unsigned short* __restrict__ DTW2, // [2048][128] pair
               float* __restrict__ XI,
               const float* __restrict__ dtb)
{
  __shared__ __align__(16) unsigned short As[128*128];
  __shared__ __align__(16) unsigned short Bs[128*128];
  const int t = threadIdx.x;
  const int mbase = blockIdx.y << 7, nbase = blockIdx.x << 7;
  const int lane = t & 63, w = t >> 6;
  const int wr = w >> 1, wc = w & 1;
  const int l16 = lane & 15, kq = lane >> 4;

  {
    const int row = t >> 1, half = (t & 1) << 5;
    const int r7 = row & 7;
    const float* src = XDf + (size_t)(mbase + row)*96 + half;
    #pragma unroll
    for (int i=0;i<4;i++){
      int g = (half >> 3) + i;
      CV8P(&As[row*128 + ((g ^ r7)<<3)], src + i*8);
    }
  }
  {
    #pragma unroll
    for (int q=0;q<8;q++){
      int idx = q*256 + t;
      int row = idx >> 4, sl = idx & 15;
      int ss  = (sl & 8) | ((sl & 7) ^ (row & 7));
      int col = (ss < 8) ? (ss<<3) : (64 + ((ss-8)<<3));
      gld16(DTW2 + (size_t)(nbase+row)*128 + col, &Bs[row*128 + sl*8]);
    }
  }
  __syncthreads();

  f32x4 acc[4][4];
  #pragma unroll
  for (int i=0;i<4;i++)
    #pragma unroll
    for (int j=0;j<4;j++) acc[i][j] = (f32x4){0.f,0.f,0.f,0.f};

  #pragma unroll
  for (int kb=0; kb<3; kb++){
    const int aoff = (kb==2) ? 8 : 0;
    const int boff = (kb==1) ? 8 : 0;
    #pragma unroll
    for (int kw=0; kw<2; kw++){
      const int sbase = kw*4 + kq;
      bf16x8 af[4];
      #pragma unroll
      for (int mf=0; mf<4; mf++){
        int ra = wr*64 + mf*16 + l16;
        int sA = ((sbase ^ (ra&7)) + aoff);
        af[mf] = *(const bf16x8*)&As[ra*128 + (sA<<3)];
      }
      #pragma unroll
      for (int nf=0; nf<4; nf++){
        int rb = wc*64 + nf*16 + l16;
        int sB = ((sbase ^ (rb&7)) + boff);
        bf16x8 bfr = *(const bf16x8*)&Bs[rb*128 + (sB<<3)];
        #pragma unroll
        for (int mf=0; mf<4; mf++)
          acc[mf][nf] = __builtin_amdgcn_mfma_f32_16x16x32_bf16(af[mf], bfr, acc[mf][nf], 0,0,0);
      }
    }
  }

  #pragma unroll
  for (int mf=0; mf<4; mf++){
    int r0 = mbase + wr*64 + mf*16 + kq*4;
    #pragma unroll
    for (int nf=0; nf<4; nf++){
      int c = nbase + wc*64 + nf*16 + l16;
      float eb = dtb[c];
      #pragma unroll
      for (int r=0;r<4;r++)
        XI[(size_t)(r0+r)*2048 + c] = softplusf(acc[mf][nf][r] + eb);
    }
  }
}

// ---------------------------------------------------------------------------
// Causal depthwise conv (k=4) + bias + SiLU: 4 rows x 8 d per thread (r14).
// ---------------------------------------------------------------------------
__global__ __launch_bounds__(256)
void conv_silu4(const float* __restrict__ xi, const float* __restrict__ cw,
                const float* __restrict__ cb, unsigned short* __restrict__ u2)
{
  const int r0 = blockIdx.x << 2;
  const int d0 = threadIdx.x << 3;
  const int tt0 = r0 & (SEQL-1);

  float wk[4][8];
  {
    const float4* cw4 = (const float4*)(cw + (size_t)d0*4);
    #pragma unroll
    for (int j=0;j<8;j++){
      float4 wj = cw4[j];
      wk[0][j]=wj.x; wk[1][j]=wj.y; wk[2][j]=wj.z; wk[3][j]=wj.w;
    }
  }
  float bias[8];
  *(float4*)&bias[0] = *(const float4*)(cb + d0);
  *(float4*)&bias[4] = *(const float4*)(cb + d0 + 4);

  float v[7][8];
#define LD8(dst, p) { *(float4*)&dst[0] = ((const float4*)(p))[0]; \
                      *(float4*)&dst[4] = ((const float4*)(p))[1]; }
  #pragma unroll
  for (int k=0;k<7;k++){
    int trel = tt0 - 3 + k;
    if (trel >= 0){
      LD8(v[k], xi + (size_t)(r0 - 3 + k)*DINNER + d0);
    } else {
      #pragma unroll
      for (int j=0;j<8;j++) v[k][j] = 0.f;
    }
  }
#undef LD8

  #pragma unroll
  for (int jrow=0; jrow<4; jrow++){
    unsigned short h8[8], l8[8];
    #pragma unroll
    for (int j=0;j<8;j++){
      float y = fmaf(v[jrow+3][j], wk[3][j], fmaf(v[jrow+2][j], wk[2][j],
                fmaf(v[jrow+1][j], wk[1][j], fmaf(v[jrow][j], wk[0][j], bias[j]))));
      float uv = siluf(y);
      split_bf(uv, h8[j], l8[j]);
    }
    unsigned short* outp = u2 + (size_t)(r0 + jrow)*4096 + d0;
    *(uint4*)outp          = *(const uint4*)h8;
    *(uint4*)(outp + 2048) = *(const uint4*)l8;
  }
}

// ---------------------------------------------------------------------------
// Chunked selective scan, PIPELINED double-buffer (r12 proven, unchanged).
// ---------------------------------------------------------------------------
template<int PASS>
__global__ __launch_bounds__(256)
void scan_chunk(const unsigned short* __restrict__ u2, float* __restrict__ dty,
                const float* __restrict__ xdbl, const float* __restrict__ zb,
                const float* __restrict__ A_log, const float* __restrict__ Dp,
                float* __restrict__ hfin, float* __restrict__ sumdt)
{
  __shared__ __align__(16) float Tdt[2][TT][256];
  __shared__ __align__(16) float Tu [2][TT][256];
  __shared__ __align__(16) float Tz [(PASS==3)?2:1][(PASS==3)?TT:1][(PASS==3)?256:4];
  __shared__ __align__(16) float Tbc[2][TT][32];

  const int tid = threadIdx.x;
  const int idx = blockIdx.x*256 + tid;
  const int d = idx & (DINNER-1);
  const int g = idx >> 11;          // uniform per block
  const int cck = g & (NC-1);
  const int bb = g >> 5;
  const int wv = tid >> 6, ln = tid & 63;
  const int dbase = (blockIdx.x << 8) & (DINNER-1);

  float A2[16];
  {
    const float* al = A_log + (size_t)d*DSTATE;
    #pragma unroll
    for (int s=0;s<16;s++) A2[s] = -expf(al[s]) * 1.44269504f;
  }
  float h[16];
  if (PASS == 1){
    #pragma unroll
    for (int s=0;s<16;s++) h[s] = 0.f;
  } else {
    const float* hp = hfin + ((size_t)g*DINNER + d)*16;
    #pragma unroll
    for (int s=0;s<16;s+=4) *(float4*)&h[s] = *(const float4*)(hp + s);
  }
  const float Dv = (PASS==3) ? Dp[d] : 0.f;

  const size_t row0 = (size_t)bb*SEQL + (size_t)cck*TC;

#define STAGE(buf, T0) do { \
    _Pragma("unroll") \
    for (int q=0;q<2;q++){ \
      int r = q*4 + wv; \
      size_t rowi = row0 + (T0) + r; \
      gld16(dty + rowi*2048 + dbase + ln*4, &Tdt[buf][r][0]); \
      const unsigned short* us = u2 + rowi*4096 + \
          ((ln < 32) ? (dbase + ln*8) : (2048 + dbase + (ln-32)*8)); \
      gld16(us, &Tu[buf][r][0]); \
      if (PASS==3) gld16(zb + rowi*2048 + dbase + ln*4, &Tz[buf][r][0]); \
    } \
    if (wv == 3){ \
      gld16(xdbl + (row0 + (T0) + (ln>>3))*96 + 64 + (ln&7)*4, &Tbc[buf][0][0]); \
    } \
  } while(0)

  STAGE(0, 0);
  asm volatile("s_waitcnt vmcnt(0)" ::: "memory");
  __builtin_amdgcn_s_barrier();
  __builtin_amdgcn_sched_barrier(0);

  float sdt = 0.f;

  for (int t0 = 0; t0 < TC; t0 += TT){
    const int cur = (t0 >> 3) & 1, nxt = cur ^ 1;
    const bool hasNext = (t0 + TT < TC);
    if (hasNext) STAGE(nxt, t0 + TT);

    if (hasNext){
      if (PASS==3){
        if (wv==3) asm volatile("s_waitcnt vmcnt(7)" ::: "memory");
        else       asm volatile("s_waitcnt vmcnt(6)" ::: "memory");
      } else {
        if (wv==3) asm volatile("s_waitcnt vmcnt(5)" ::: "memory");
        else       asm volatile("s_waitcnt vmcnt(4)" ::: "memory");
      }
    } else {
      asm volatile("s_waitcnt vmcnt(0)" ::: "memory");
    }
    __builtin_amdgcn_s_barrier();
    __builtin_amdgcn_sched_barrier(0);

    #pragma unroll
    for (int tt=0; tt<TT; tt++){
      float dtc = Tdt[cur][tt][tid];
      const unsigned short* tur = (const unsigned short*)&Tu[cur][tt][0];
      float uc = __uint_as_float((u32)tur[tid] << 16)
               + __uint_as_float((u32)tur[256+tid] << 16);
      float Bv[16], Cv[16];
      #pragma unroll
      for (int q=0;q<4;q++) *(float4*)&Bv[q*4] = *(const float4*)&Tbc[cur][tt][q*4];
      if (PASS==3){
        #pragma unroll
        for (int q=0;q<4;q++) *(float4*)&Cv[q*4] = *(const float4*)&Tbc[cur][tt][16+q*4];
      }
      if (PASS==1) sdt += dtc;
      float du = dtc*uc;
      float y = 0.f;
      #pragma unroll
      for (int s=0;s<16;s++){
        float dA = exp2f(dtc*A2[s]);
        h[s] = fmaf(dA, h[s], du*Bv[s]);
        if (PASS==3) y = fmaf(h[s], Cv[s], y);
      }
      if (PASS==3){
        float zc = Tz[cur][tt][tid];
        y = fmaf(uc, Dv, y);
        float gv = y * siluf(zc);
        unsigned short gh, gl;
        split_bf(gv, gh, gl);
        Tdt[cur][tt][tid] = __uint_as_float((u32)gh | ((u32)gl << 16));
      }
    }

    if (PASS==3) asm volatile("s_waitcnt lgkmcnt(0)" ::: "memory");
    __builtin_amdgcn_s_barrier();
    __builtin_amdgcn_sched_barrier(0);

    if (PASS==3){
      #pragma unroll
      for (int q=0;q<2;q++){
        int r = q*4 + wv;
        size_t rowi = row0 + t0 + r;
        const u32* T = (const u32*)&Tdt[cur][r][0];
        int o0 = ln*4;
        u32 vals[4];
        if (ln < 32){
          #pragma unroll
          for (int k=0;k<4;k++){
            int i2 = (o0+k)*2;
            vals[k] = (T[i2] & 0xFFFFu) | (T[i2+1] << 16);
          }
        } else {
          #pragma unroll
          for (int k=0;k<4;k++){
            int i2 = (o0+k-128)*2;
            vals[k] = (T[i2] >> 16) | (T[i2+1] & 0xFFFF0000u);
          }
        }
        *(float4*)(dty + rowi*2048 + dbase + o0) = *(const float4*)vals;
      }
    }
  }
#undef STAGE

  if (PASS==1){
    float* hp = hfin + ((size_t)g*DINNER + d)*16;
    #pragma unroll
    for (int s=0;s<16;s+=4) *(float4*)(hp + s) = *(const float4*)&h[s];
    sumdt[(size_t)g*DINNER + d] = sdt;
  }
}

// ---------------------------------------------------------------------------
// Propagate chunk-initial states: in-place hfin[c] := H_init(c).
// ---------------------------------------------------------------------------
__global__ __launch_bounds__(256)
void scan_prop(const float* __restrict__ A_log, float* __restrict__ hfin,
               const float* __restrict__ sumdt)
{
  int idx = blockIdx.x*256 + threadIdx.x;
  int s = idx & 15;
  int d = (idx >> 4) & (DINNER-1);
  int b = idx >> 15;
  float A2 = -expf(A_log[(size_t)d*DSTATE + s]) * 1.44269504f;
  float H = 0.f;
  size_t hbase = ((size_t)b*NC*DINNER + d)*16 + s;
  size_t sbase = (size_t)b*NC*DINNER + d;
  for (int c=0;c<NC;c++){
    float P   = exp2f(A2 * sumdt[sbase + (size_t)c*DINNER]);
    float tmp = hfin[hbase + (size_t)c*DINNER*16];
    hfin[hbase + (size_t)c*DINNER*16] = H;
    H = fmaf(P, H, tmp);
  }
}

// ---------------------------------------------------------------------------
// Launcher.  Fixed (52.95 MB): INW2 33.55 + OUTWG 16.78 + XPW2 1.57 +
// DTW2 1.05.  Per batch (58.72 MB).  NB=4 -> 287.8 MB (< 305.1 known-good).
// ---------------------------------------------------------------------------
extern "C" void kernel_launch(void* const* d_in, const int* in_sizes, int n_in,
                              void* d_out, int out_size, void* d_ws, size_t ws_size,
                              hipStream_t stream)
{
  const float* x    = (const float*)d_in[0];
  const float* in_w = (const float*)d_in[1];
  const float* cw   = (const float*)d_in[2];
  const float* cb   = (const float*)d_in[3];
  const float* xpw  = (const float*)d_in[4];
  const float* dtw  = (const float*)d_in[5];
  const float* dtb  = (const float*)d_in[6];
  const float* A_log= (const float*)d_in[7];
  const float* Dp   = (const float*)d_in[8];
  const float* ow   = (const float*)d_in[9];
  const float* nw   = (const float*)d_in[10];
  const float* nb   = (const float*)d_in[11];
  float* outF = (float*)d_out;

  const size_t fixedB = 33554432ULL + 16777216ULL + 1572864ULL + 1048576ULL;
  const size_t perB   = 58720256ULL;
  int NB = 4;
  while (NB > 1 && fixedB + (size_t)NB*perB > ws_size) NB >>= 1;
  const int Mc = NB * SEQL;
  const int nchunk = SEQB / NB;

  unsigned short* INW2  = (unsigned short*)d_ws;                 // [2][4096][2048]
  unsigned short* OUTWG = INW2 + (size_t)2*4096*2048;            // [2][1024][4096]
  unsigned short* XPW2  = OUTWG + (size_t)2*1024*4096;           // [2][96][4096]
  unsigned short* DTW2  = XPW2 + (size_t)2*96*4096;              // [2][2048][128]
  char* dyn = (char*)(DTW2 + (size_t)2*2048*128);

  unsigned short* SH = (unsigned short*)dyn;                     // Mc*2048 ushort
  float* XD = (float*)dyn;                                       // Mc*96  (alias SH)
  float* HF = (float*)(dyn + (size_t)Mc*384);                    // Mc*512 (alias SH)
  float* SD = (float*)(dyn + (size_t)Mc*2432);                   // Mc*32  (alias SH)
  float* XI = (float*)(dyn + (size_t)Mc*4096);                   // Mc*2048 f32
  float* ZB = XI + (size_t)Mc*2048;                              // Mc*2048
  unsigned short* U2 = (unsigned short*)(ZB + (size_t)Mc*2048);  // Mc*4096 ushort

  // Weight pre-splits
  wsplit2<<<8192, 256, 0, stream>>>(in_w, INW2, 1024, 8);
  wsplit2<<<384,  256, 0, stream>>>(xpw,  XPW2, 2048, 9);
  wsplit2<<<256,  256, 0, stream>>>(dtw,  DTW2, 64, 4);
  wsplit_og<<<4096, 256, 0, stream>>>(ow, OUTWG);

  for (int c = 0; c < nchunk; ++c){
    const size_t rowoff = (size_t)c * Mc;
    const float* xrows = x + rowoff * DMODEL;
    float* X1 = outF + rowoff * DMODEL;     // layer-0 out / final out rows

    for (int l = 0; l < 2; ++l){
      const float* Al = A_log + (size_t)l*DINNER*DSTATE;

      // 1. LayerNorm (+ residual for layer 1) -> SH pair
      ln_split2<<<Mc, 256, 0, stream>>>(
          (l==0) ? xrows : X1, (l==0) ? nullptr : xrows,
          nw + (size_t)l*DMODEL, nb + (size_t)l*DMODEL, SH);

      // 2. in_proj fused xi|z (256x256 8-wave, single-buf): -> XI / ZB
      mgemm_in8<<<dim3(16, Mc/256), 512, 0, stream>>>(
          SH, INW2 + (size_t)l*4096*2048, XI, ZB);

      // 3. causal conv + bias + SiLU: XI -> U2 (split pair), 4-row threads
      conv_silu4<<<Mc/4, 256, 0, stream>>>(
          XI, cw + (size_t)l*DINNER*4, cb + (size_t)l*DINNER, U2);

      // 4. x_proj (pipelined pair GEMM) -> XD
      xproj_pair<<<Mc/32, 256, 0, stream>>>(
          U2, XPW2 + (size_t)l*96*4096, XD);

      // 5. dt_proj MFMA + bias + softplus -> XI (xi dead after conv)
      mgemm_dt2<<<dim3(16, Mc/128), 256, 0, stream>>>(
          XD, DTW2 + (size_t)l*2048*128, XI, dtb + (size_t)l*DINNER);

      // 6. chunked scan (pipelined); pass 3 writes grouped-plane gy over XI
      scan_chunk<1><<<NB*NC*8, 256, 0, stream>>>(
          U2, XI, XD, ZB, Al, Dp + (size_t)l*DINNER, HF, SD);
      scan_prop<<<NB*128, 256, 0, stream>>>(Al, HF, SD);
      scan_chunk<3><<<NB*NC*8, 256, 0, stream>>>(
          U2, XI, XD, ZB, Al, Dp + (size_t)l*DINNER, HF, SD);

      // 7. out_proj (128x128 dbuf+vmcnt): grouped-A x grouped-B -> X1 rows
      mgemm_out3<<<dim3(8, Mc/128), 256, 0, stream>>>(
          (const unsigned short*)XI, OUTWG + (size_t)l*1024*4096, X1);
    }
  }
}